// Round 1
// baseline (1268.791 us; speedup 1.0000x reference)
//
#include <hip/hip_runtime.h>
#include <hip/hip_bf16.h>

#define NN 50000
#define EE 800000
#define GG 16
#define IN_DIM 256
#define HID 64
#define NEG 0.2f
#define NPB 16

__device__ inline float wred_sum(float v) {
    for (int o = 32; o > 0; o >>= 1) v += __shfl_xor(v, o, 64);
    return v;
}
__device__ inline float wred_max(float v) {
    for (int o = 32; o > 0; o >>= 1) v = fmaxf(v, __shfl_xor(v, o, 64));
    return v;
}

// ---- degree + edge_attr sum per dst ----
__global__ __launch_bounds__(256) void deg_kernel(const int* __restrict__ ei,
                                                  const float* __restrict__ eattr,
                                                  int* __restrict__ deg,
                                                  float* __restrict__ esum) {
    int e = blockIdx.x * 256 + threadIdx.x;
    if (e >= EE) return;
    int d = ei[EE + e];
    atomicAdd(&deg[d], 1);
    atomicAdd(&esum[d], eattr[e]);
}

// ---- single-block exclusive scan over deg; also mean_e, inv_deg, pos ----
__global__ __launch_bounds__(1024) void scan_kernel(const int* __restrict__ deg,
                                                    const float* __restrict__ esum,
                                                    int* __restrict__ row_off,
                                                    int* __restrict__ pos,
                                                    float* __restrict__ mean_e,
                                                    float* __restrict__ inv_deg) {
    __shared__ int buf[1024];
    __shared__ int carry;
    if (threadIdx.x == 0) carry = 0;
    __syncthreads();
    for (int base = 0; base < NN; base += 1024) {
        int i = base + threadIdx.x;
        int v = (i < NN) ? deg[i] : 0;
        buf[threadIdx.x] = v;
        __syncthreads();
        for (int ofs = 1; ofs < 1024; ofs <<= 1) {
            int t = (threadIdx.x >= ofs) ? buf[threadIdx.x - ofs] : 0;
            __syncthreads();
            buf[threadIdx.x] += t;
            __syncthreads();
        }
        int incl = buf[threadIdx.x];
        int excl = incl - v;
        if (i < NN) {
            int ro = carry + excl;
            row_off[i] = ro;
            pos[i] = ro;
            float idg = 1.0f / fmaxf((float)v, 1.0f);
            inv_deg[i] = idg;
            mean_e[i] = esum[i] * idg;
        }
        __syncthreads();
        if (threadIdx.x == 1023) carry += incl;
        __syncthreads();
    }
    if (threadIdx.x == 0) row_off[NN] = carry;
}

// ---- fill CSR buckets ----
__global__ __launch_bounds__(256) void fill_kernel(const int* __restrict__ ei,
                                                   const float* __restrict__ eattr,
                                                   int* __restrict__ pos,
                                                   int* __restrict__ csr_src,
                                                   float* __restrict__ csr_e) {
    int e = blockIdx.x * 256 + threadIdx.x;
    if (e >= EE) return;
    int d = ei[EE + e];
    int p = atomicAdd(&pos[d], 1);
    csr_src[p] = ei[e];
    csr_e[p] = eattr[e];
}

// ---- transpose sage weights: wl[64][256], wr[64][256] -> wt[k*128+j] ----
__global__ void transpose2_kernel(const float* __restrict__ wl,
                                  const float* __restrict__ wr,
                                  float* __restrict__ wt) {
    int k = blockIdx.x;      // 0..255
    int j = threadIdx.x;     // 0..127
    float v = (j < 64) ? wl[j * 256 + k] : wr[(j - 64) * 256 + k];
    wt[k * 128 + j] = v;
}

// ---- transpose gat weight: w[H64][64] -> wt[k*H64+j] ----
__global__ void transpose_gat_kernel(const float* __restrict__ w,
                                     float* __restrict__ wt, int H64) {
    int k = blockIdx.x;   // 0..63
    int j = threadIdx.x;  // 0..127
    if (j < H64) wt[k * H64 + j] = w[j * 64 + k];
}

// ---- x @ [wl|wr].T : N x 256 -> N x 128 (xl, xr) ----
__global__ __launch_bounds__(128) void sage_mm_kernel(const float* __restrict__ x,
                                                      const float* __restrict__ wt,
                                                      float* __restrict__ xl,
                                                      float* __restrict__ xr) {
    __shared__ float xs[NPB * 256];
    int node0 = blockIdx.x * NPB;
    for (int t = threadIdx.x; t < NPB * 256; t += 128)
        xs[t] = x[node0 * 256 + t];
    __syncthreads();
    int j = threadIdx.x;
    float acc[NPB];
#pragma unroll
    for (int n = 0; n < NPB; n++) acc[n] = 0.f;
    for (int k = 0; k < 256; k++) {
        float wv = wt[k * 128 + j];
#pragma unroll
        for (int n = 0; n < NPB; n++) acc[n] = fmaf(xs[n * 256 + k], wv, acc[n]);
    }
    for (int n = 0; n < NPB; n++) {
        int node = node0 + n;
        if (j < 64) xl[node * 64 + j] = acc[n];
        else        xr[node * 64 + (j - 64)] = acc[n];
    }
}

// ---- h @ W.T for GAT: N x 64 -> N x H64 ----
__global__ __launch_bounds__(128) void proj_mm_kernel(const float* __restrict__ hin,
                                                      const float* __restrict__ wt,
                                                      float* __restrict__ hproj, int H64) {
    __shared__ float xs[NPB * 64];
    int node0 = blockIdx.x * NPB;
    for (int t = threadIdx.x; t < NPB * 64; t += 128)
        xs[t] = hin[node0 * 64 + t];
    __syncthreads();
    int j = threadIdx.x;
    float acc[NPB];
#pragma unroll
    for (int n = 0; n < NPB; n++) acc[n] = 0.f;
    if (j < H64) {
        for (int k = 0; k < 64; k++) {
            float wv = wt[k * H64 + j];
#pragma unroll
            for (int n = 0; n < NPB; n++) acc[n] = fmaf(xs[n * 64 + k], wv, acc[n]);
        }
        for (int n = 0; n < NPB; n++) {
            int node = node0 + n;
            hproj[node * H64 + j] = acc[n];
        }
    }
}

// ---- SAGE aggregation + combine + relu ----
__global__ __launch_bounds__(256) void sage_agg_kernel(const float* __restrict__ xl,
                                                       const float* __restrict__ xr,
                                                       const float* __restrict__ bl,
                                                       const float* __restrict__ inv_deg,
                                                       const int* __restrict__ row_off,
                                                       const int* __restrict__ csr_src,
                                                       float* __restrict__ hout) {
    int wid = blockIdx.x * 4 + (threadIdx.x >> 6);
    int lane = threadIdx.x & 63;
    if (wid >= NN) return;
    int r0 = row_off[wid], r1 = row_off[wid + 1];
    float sum = 0.f;
    for (int idx = r0; idx < r1; ++idx) {
        int s = csr_src[idx];
        sum += xl[s * 64 + lane];
    }
    float v = sum * inv_deg[wid] + bl[lane] + xr[wid * 64 + lane];
    hout[wid * 64 + lane] = fmaxf(v, 0.f);
}

// ---- per-(node,head) attention source/dest scalars ----
__global__ __launch_bounds__(256) void attval_kernel(const float* __restrict__ hproj,
                                                     const float* __restrict__ a_s,
                                                     const float* __restrict__ a_d,
                                                     float* __restrict__ sval,
                                                     float* __restrict__ dval, int H) {
    int wid = (blockIdx.x * 256 + threadIdx.x) >> 6;
    int lane = threadIdx.x & 63;
    if (wid >= NN) return;
    for (int h = 0; h < H; ++h) {
        float hp = hproj[wid * H * 64 + h * 64 + lane];
        float sv = wred_sum(hp * a_s[h * 64 + lane]);
        float dv = wred_sum(hp * a_d[h * 64 + lane]);
        if (lane == 0) {
            sval[wid * H + h] = sv;
            dval[wid * H + h] = dv;
        }
    }
}

__device__ inline float lrelu(float a) { return a > 0.f ? a : NEG * a; }

// ---- GAT: softmax over incoming edges (+self loop) and aggregate ----
__global__ __launch_bounds__(256) void gat_kernel(const float* __restrict__ hproj,
                                                  const float* __restrict__ sval,
                                                  const float* __restrict__ dval,
                                                  const float* __restrict__ we,
                                                  const float* __restrict__ ae,
                                                  const float* __restrict__ bias,
                                                  const float* __restrict__ mean_e,
                                                  const int* __restrict__ row_off,
                                                  const int* __restrict__ csr_src,
                                                  const float* __restrict__ csr_e,
                                                  float* __restrict__ hout, int H) {
    int wid = blockIdx.x * 4 + (threadIdx.x >> 6);
    int lane = threadIdx.x & 63;
    if (wid >= NN) return;
    int H64 = H * 64;
    int r0 = row_off[wid], r1 = row_off[wid + 1];
    float me = mean_e[wid];
    float head_sum = 0.f;
    for (int h = 0; h < H; ++h) {
        float wedot = wred_sum(we[h * 64 + lane] * ae[h * 64 + lane]);
        float dv = dval[wid * H + h];
        float a_self = lrelu(sval[wid * H + h] + dv + me * wedot);
        // pass A: max
        float m = a_self;
        for (int idx = r0 + lane; idx < r1; idx += 64) {
            int s = csr_src[idx];
            float a = lrelu(sval[s * H + h] + dv + csr_e[idx] * wedot);
            m = fmaxf(m, a);
        }
        m = wred_max(m);
        // pass A2: denom
        float den = 0.f;
        for (int idx = r0 + lane; idx < r1; idx += 64) {
            int s = csr_src[idx];
            float a = lrelu(sval[s * H + h] + dv + csr_e[idx] * wedot);
            den += expf(a - m);
        }
        den = wred_sum(den) + expf(a_self - m);
        float inv_den = 1.0f / den;
        // pass B: weighted aggregate, lane = channel
        float acc = expf(a_self - m) * inv_den * hproj[wid * H64 + h * 64 + lane];
        for (int idx = r0; idx < r1; ++idx) {
            int s = csr_src[idx];
            float a = lrelu(sval[s * H + h] + dv + csr_e[idx] * wedot);
            float c = expf(a - m) * inv_den;
            acc = fmaf(c, hproj[s * H64 + h * 64 + lane], acc);
        }
        head_sum += acc;
    }
    float out = head_sum / (float)H + bias[lane];
    hout[wid * 64 + lane] = fmaxf(out, 0.f);
}

// ---- masked mean pool (atomic accumulate) ----
__global__ __launch_bounds__(256) void pool_kernel(const float* __restrict__ h,
                                                   const int* __restrict__ ntype,
                                                   const int* __restrict__ batch,
                                                   float* __restrict__ pool,
                                                   float* __restrict__ cnt) {
    int wid = blockIdx.x * 4 + (threadIdx.x >> 6);
    int lane = threadIdx.x & 63;
    if (wid >= NN) return;
    int t = ntype[wid];
    if (t == 1 || t == 2) {
        int g = batch[wid];
        atomicAdd(&pool[((t - 1) * GG + g) * 64 + lane], h[wid * 64 + lane]);
        if (lane == 0) atomicAdd(&cnt[(t - 1) * GG + g], 1.0f);
    }
}

// ---- final MLP ----
__global__ __launch_bounds__(256) void mlp_kernel(const float* __restrict__ pool,
                                                  const float* __restrict__ cnt,
                                                  const float* __restrict__ w1,
                                                  const float* __restrict__ b1,
                                                  const float* __restrict__ w2,
                                                  const float* __restrict__ b2,
                                                  float* __restrict__ out) {
    __shared__ float ro[GG * 128];
    __shared__ float hid[GG * 64];
    int tid = threadIdx.x;
    for (int t = tid; t < GG * 128; t += 256) {
        int g = t >> 7;
        int j = t & 127;
        int part = j >> 6;
        float c = fmaxf(cnt[part * GG + g], 1.0f);
        ro[t] = pool[(part * GG + g) * 64 + (j & 63)] / c;
    }
    __syncthreads();
    for (int t = tid; t < GG * 64; t += 256) {
        int g = t >> 6;
        int i = t & 63;
        float s = b1[i];
        for (int j = 0; j < 128; j++) s = fmaf(ro[g * 128 + j], w1[i * 128 + j], s);
        hid[t] = fmaxf(s, 0.f);
    }
    __syncthreads();
    if (tid < GG) {
        float s = b2[0];
        for (int i = 0; i < 64; i++) s = fmaf(hid[tid * 64 + i], w2[i], s);
        out[tid] = s;
    }
}

extern "C" void kernel_launch(void* const* d_in, const int* in_sizes, int n_in,
                              void* d_out, int out_size, void* d_ws, size_t ws_size,
                              hipStream_t stream) {
    const float* x       = (const float*)d_in[0];
    const int*   ei      = (const int*)d_in[1];
    const int*   ntype   = (const int*)d_in[2];
    const float* eattr   = (const float*)d_in[3];
    const int*   batch   = (const int*)d_in[4];
    const float* sage_wl = (const float*)d_in[5];
    const float* sage_bl = (const float*)d_in[6];
    const float* sage_wr = (const float*)d_in[7];
    const float* mlp_w1  = (const float*)d_in[8];
    const float* mlp_b1  = (const float*)d_in[9];
    const float* mlp_w2  = (const float*)d_in[10];
    const float* mlp_b2  = (const float*)d_in[11];
    const float* gw[3]  = {(const float*)d_in[12], (const float*)d_in[18], (const float*)d_in[24]};
    const float* gas[3] = {(const float*)d_in[13], (const float*)d_in[19], (const float*)d_in[25]};
    const float* gad[3] = {(const float*)d_in[14], (const float*)d_in[20], (const float*)d_in[26]};
    const float* gwe[3] = {(const float*)d_in[15], (const float*)d_in[21], (const float*)d_in[27]};
    const float* gae[3] = {(const float*)d_in[16], (const float*)d_in[22], (const float*)d_in[28]};
    const float* gb[3]  = {(const float*)d_in[17], (const float*)d_in[23], (const float*)d_in[29]};

    char* base = (char*)d_ws;
    size_t o = 0;
    auto alloc = [&](size_t bytes) -> char* {
        char* p = base + o;
        o = (o + bytes + 255) & ~(size_t)255;
        return p;
    };
    int*   deg     = (int*)  alloc(NN * 4);
    float* esum    = (float*)alloc(NN * 4);
    float* mean_e  = (float*)alloc(NN * 4);
    float* inv_deg = (float*)alloc(NN * 4);
    int*   row_off = (int*)  alloc((NN + 1) * 4);
    int*   pos     = (int*)  alloc(NN * 4);
    int*   csr_src = (int*)  alloc((size_t)EE * 4);
    float* csr_e   = (float*)alloc((size_t)EE * 4);
    float* xl      = (float*)alloc((size_t)NN * 64 * 4);
    float* xr      = (float*)alloc((size_t)NN * 64 * 4);
    float* hA      = (float*)alloc((size_t)NN * 64 * 4);
    float* hB      = (float*)alloc((size_t)NN * 64 * 4);
    float* hproj   = (float*)alloc((size_t)NN * 128 * 4);
    float* sval    = (float*)alloc((size_t)NN * 2 * 4);
    float* dval    = (float*)alloc((size_t)NN * 2 * 4);
    float* wt      = (float*)alloc(256 * 128 * 4);
    float* wtg     = (float*)alloc(64 * 128 * 4);
    float* pools   = (float*)alloc(2 * GG * 64 * 4);
    float* cnt     = (float*)alloc(2 * GG * 4);

    hipMemsetAsync(deg, 0, NN * 4, stream);
    hipMemsetAsync(esum, 0, NN * 4, stream);
    hipMemsetAsync(pools, 0, 2 * GG * 64 * 4, stream);
    hipMemsetAsync(cnt, 0, 2 * GG * 4, stream);

    deg_kernel<<<EE / 256, 256, 0, stream>>>(ei, eattr, deg, esum);
    scan_kernel<<<1, 1024, 0, stream>>>(deg, esum, row_off, pos, mean_e, inv_deg);
    fill_kernel<<<EE / 256, 256, 0, stream>>>(ei, eattr, pos, csr_src, csr_e);

    transpose2_kernel<<<256, 128, 0, stream>>>(sage_wl, sage_wr, wt);
    sage_mm_kernel<<<NN / NPB, 128, 0, stream>>>(x, wt, xl, xr);
    sage_agg_kernel<<<NN / 4, 256, 0, stream>>>(xl, xr, sage_bl, inv_deg, row_off, csr_src, hA);

    float* hin = hA;
    float* hout = hB;
    for (int L = 0; L < 3; ++L) {
        int H = (L == 2) ? 1 : 2;
        int H64 = H * 64;
        transpose_gat_kernel<<<64, 128, 0, stream>>>(gw[L], wtg, H64);
        proj_mm_kernel<<<NN / NPB, 128, 0, stream>>>(hin, wtg, hproj, H64);
        attval_kernel<<<NN / 4, 256, 0, stream>>>(hproj, gas[L], gad[L], sval, dval, H);
        gat_kernel<<<NN / 4, 256, 0, stream>>>(hproj, sval, dval, gwe[L], gae[L], gb[L],
                                               mean_e, row_off, csr_src, csr_e, hout, H);
        float* tmp = hin; hin = hout; hout = tmp;
    }
    // final features now in hin
    pool_kernel<<<NN / 4, 256, 0, stream>>>(hin, ntype, batch, pools, cnt);
    mlp_kernel<<<1, 256, 0, stream>>>(pools, cnt, mlp_w1, mlp_b1, mlp_w2, mlp_b2, (float*)d_out);
}

// Round 2
// 1101.437 us; speedup vs baseline: 1.1519x; 1.1519x over previous
//
#include <hip/hip_runtime.h>
#include <hip/hip_bf16.h>

#define NN 50000
#define EE 800000
#define GG 16
#define IN_DIM 256
#define HID 64
#define NEG 0.2f
#define NPB 16

__device__ inline float wred_sum(float v) {
    for (int o = 32; o > 0; o >>= 1) v += __shfl_xor(v, o, 64);
    return v;
}
__device__ inline float wred_max(float v) {
    for (int o = 32; o > 0; o >>= 1) v = fmaxf(v, __shfl_xor(v, o, 64));
    return v;
}

// ---- degree + edge_attr sum per dst ----
__global__ __launch_bounds__(256) void deg_kernel(const int* __restrict__ ei,
                                                  const float* __restrict__ eattr,
                                                  int* __restrict__ deg,
                                                  float* __restrict__ esum) {
    int e = blockIdx.x * 256 + threadIdx.x;
    if (e >= EE) return;
    int d = ei[EE + e];
    atomicAdd(&deg[d], 1);
    atomicAdd(&esum[d], eattr[e]);
}

// ---- single-block exclusive scan over deg; also mean_e, inv_deg, pos ----
__global__ __launch_bounds__(1024) void scan_kernel(const int* __restrict__ deg,
                                                    const float* __restrict__ esum,
                                                    int* __restrict__ row_off,
                                                    int* __restrict__ pos,
                                                    float* __restrict__ mean_e,
                                                    float* __restrict__ inv_deg) {
    __shared__ int buf[1024];
    __shared__ int carry;
    if (threadIdx.x == 0) carry = 0;
    __syncthreads();
    for (int base = 0; base < NN; base += 1024) {
        int i = base + threadIdx.x;
        int v = (i < NN) ? deg[i] : 0;
        buf[threadIdx.x] = v;
        __syncthreads();
        for (int ofs = 1; ofs < 1024; ofs <<= 1) {
            int t = (threadIdx.x >= ofs) ? buf[threadIdx.x - ofs] : 0;
            __syncthreads();
            buf[threadIdx.x] += t;
            __syncthreads();
        }
        int incl = buf[threadIdx.x];
        int excl = incl - v;
        if (i < NN) {
            int ro = carry + excl;
            row_off[i] = ro;
            pos[i] = ro;
            float idg = 1.0f / fmaxf((float)v, 1.0f);
            inv_deg[i] = idg;
            mean_e[i] = esum[i] * idg;
        }
        __syncthreads();
        if (threadIdx.x == 1023) carry += incl;
        __syncthreads();
    }
    if (threadIdx.x == 0) row_off[NN] = carry;
}

// ---- fill CSR buckets ----
__global__ __launch_bounds__(256) void fill_kernel(const int* __restrict__ ei,
                                                   const float* __restrict__ eattr,
                                                   int* __restrict__ pos,
                                                   int* __restrict__ csr_src,
                                                   float* __restrict__ csr_e) {
    int e = blockIdx.x * 256 + threadIdx.x;
    if (e >= EE) return;
    int d = ei[EE + e];
    int p = atomicAdd(&pos[d], 1);
    csr_src[p] = ei[e];
    csr_e[p] = eattr[e];
}

// ---- transpose sage weights: wl[64][256], wr[64][256] -> wt[k*128+j] ----
__global__ void transpose2_kernel(const float* __restrict__ wl,
                                  const float* __restrict__ wr,
                                  float* __restrict__ wt) {
    int k = blockIdx.x;      // 0..255
    int j = threadIdx.x;     // 0..127
    float v = (j < 64) ? wl[j * 256 + k] : wr[(j - 64) * 256 + k];
    wt[k * 128 + j] = v;
}

// ---- transpose gat weight: w[H64][64] -> wt[k*H64+j] ----
__global__ void transpose_gat_kernel(const float* __restrict__ w,
                                     float* __restrict__ wt, int H64) {
    int k = blockIdx.x;   // 0..63
    int j = threadIdx.x;  // 0..127
    if (j < H64) wt[k * H64 + j] = w[j * 64 + k];
}

// ---- x @ [wl|wr].T : N x 256 -> N x 128 (xl, xr) ----
__global__ __launch_bounds__(128) void sage_mm_kernel(const float* __restrict__ x,
                                                      const float* __restrict__ wt,
                                                      float* __restrict__ xl,
                                                      float* __restrict__ xr) {
    __shared__ float xs[NPB * 256];
    int node0 = blockIdx.x * NPB;
    for (int t = threadIdx.x; t < NPB * 256; t += 128)
        xs[t] = x[node0 * 256 + t];
    __syncthreads();
    int j = threadIdx.x;
    float acc[NPB];
#pragma unroll
    for (int n = 0; n < NPB; n++) acc[n] = 0.f;
    for (int k = 0; k < 256; k++) {
        float wv = wt[k * 128 + j];
#pragma unroll
        for (int n = 0; n < NPB; n++) acc[n] = fmaf(xs[n * 256 + k], wv, acc[n]);
    }
    for (int n = 0; n < NPB; n++) {
        int node = node0 + n;
        if (j < 64) xl[node * 64 + j] = acc[n];
        else        xr[node * 64 + (j - 64)] = acc[n];
    }
}

// ---- h @ W.T for GAT: N x 64 -> N x H64 ----
__global__ __launch_bounds__(128) void proj_mm_kernel(const float* __restrict__ hin,
                                                      const float* __restrict__ wt,
                                                      float* __restrict__ hproj, int H64) {
    __shared__ float xs[NPB * 64];
    int node0 = blockIdx.x * NPB;
    for (int t = threadIdx.x; t < NPB * 64; t += 128)
        xs[t] = hin[node0 * 64 + t];
    __syncthreads();
    int j = threadIdx.x;
    float acc[NPB];
#pragma unroll
    for (int n = 0; n < NPB; n++) acc[n] = 0.f;
    if (j < H64) {
        for (int k = 0; k < 64; k++) {
            float wv = wt[k * H64 + j];
#pragma unroll
            for (int n = 0; n < NPB; n++) acc[n] = fmaf(xs[n * 64 + k], wv, acc[n]);
        }
        for (int n = 0; n < NPB; n++) {
            int node = node0 + n;
            hproj[node * H64 + j] = acc[n];
        }
    }
}

// ---- SAGE aggregation + combine + relu ----
__global__ __launch_bounds__(256) void sage_agg_kernel(const float* __restrict__ xl,
                                                       const float* __restrict__ xr,
                                                       const float* __restrict__ bl,
                                                       const float* __restrict__ inv_deg,
                                                       const int* __restrict__ row_off,
                                                       const int* __restrict__ csr_src,
                                                       float* __restrict__ hout) {
    int wid = blockIdx.x * 4 + (threadIdx.x >> 6);
    int lane = threadIdx.x & 63;
    if (wid >= NN) return;
    int r0 = row_off[wid], r1 = row_off[wid + 1];
    float sum = 0.f;
    for (int idx = r0; idx < r1; ++idx) {
        int s = csr_src[idx];
        sum += xl[s * 64 + lane];
    }
    float v = sum * inv_deg[wid] + bl[lane] + xr[wid * 64 + lane];
    hout[wid * 64 + lane] = fmaxf(v, 0.f);
}

// ---- per-(node,head) attention source/dest scalars ----
__global__ __launch_bounds__(256) void attval_kernel(const float* __restrict__ hproj,
                                                     const float* __restrict__ a_s,
                                                     const float* __restrict__ a_d,
                                                     float* __restrict__ sval,
                                                     float* __restrict__ dval, int H) {
    int wid = (blockIdx.x * 256 + threadIdx.x) >> 6;
    int lane = threadIdx.x & 63;
    if (wid >= NN) return;
    for (int h = 0; h < H; ++h) {
        float hp = hproj[wid * H * 64 + h * 64 + lane];
        float sv = wred_sum(hp * a_s[h * 64 + lane]);
        float dv = wred_sum(hp * a_d[h * 64 + lane]);
        if (lane == 0) {
            sval[wid * H + h] = sv;
            dval[wid * H + h] = dv;
        }
    }
}

__device__ inline float lrelu(float a) { return a > 0.f ? a : NEG * a; }

// ---- GAT: softmax over incoming edges (+self loop) and aggregate ----
__global__ __launch_bounds__(256) void gat_kernel(const float* __restrict__ hproj,
                                                  const float* __restrict__ sval,
                                                  const float* __restrict__ dval,
                                                  const float* __restrict__ we,
                                                  const float* __restrict__ ae,
                                                  const float* __restrict__ bias,
                                                  const float* __restrict__ mean_e,
                                                  const int* __restrict__ row_off,
                                                  const int* __restrict__ csr_src,
                                                  const float* __restrict__ csr_e,
                                                  float* __restrict__ hout, int H) {
    int wid = blockIdx.x * 4 + (threadIdx.x >> 6);
    int lane = threadIdx.x & 63;
    if (wid >= NN) return;
    int H64 = H * 64;
    int r0 = row_off[wid], r1 = row_off[wid + 1];
    float me = mean_e[wid];
    float head_sum = 0.f;
    for (int h = 0; h < H; ++h) {
        float wedot = wred_sum(we[h * 64 + lane] * ae[h * 64 + lane]);
        float dv = dval[wid * H + h];
        float a_self = lrelu(sval[wid * H + h] + dv + me * wedot);
        // pass A: max
        float m = a_self;
        for (int idx = r0 + lane; idx < r1; idx += 64) {
            int s = csr_src[idx];
            float a = lrelu(sval[s * H + h] + dv + csr_e[idx] * wedot);
            m = fmaxf(m, a);
        }
        m = wred_max(m);
        // pass A2: denom
        float den = 0.f;
        for (int idx = r0 + lane; idx < r1; idx += 64) {
            int s = csr_src[idx];
            float a = lrelu(sval[s * H + h] + dv + csr_e[idx] * wedot);
            den += expf(a - m);
        }
        den = wred_sum(den) + expf(a_self - m);
        float inv_den = 1.0f / den;
        // pass B: weighted aggregate, lane = channel
        float acc = expf(a_self - m) * inv_den * hproj[wid * H64 + h * 64 + lane];
        for (int idx = r0; idx < r1; ++idx) {
            int s = csr_src[idx];
            float a = lrelu(sval[s * H + h] + dv + csr_e[idx] * wedot);
            float c = expf(a - m) * inv_den;
            acc = fmaf(c, hproj[s * H64 + h * 64 + lane], acc);
        }
        head_sum += acc;
    }
    float out = head_sum / (float)H + bias[lane];
    hout[wid * 64 + lane] = fmaxf(out, 0.f);
}

// ---- masked mean pool: batch is SORTED -> register accumulate per wave chunk,
//      flush on graph boundary. Avoids the 2M-atomic contention storm. ----
__global__ __launch_bounds__(256) void pool_kernel(const float* __restrict__ h,
                                                   const int* __restrict__ ntype,
                                                   const int* __restrict__ batch,
                                                   float* __restrict__ pool,
                                                   float* __restrict__ cnt) {
    int nwaves = gridDim.x * 4;
    int wid = blockIdx.x * 4 + (threadIdx.x >> 6);
    int lane = threadIdx.x & 63;
    int chunk = (NN + nwaves - 1) / nwaves;
    int n0 = wid * chunk;
    int n1 = min(n0 + chunk, NN);
    if (n0 >= NN) return;
    float acc1 = 0.f, acc2 = 0.f;
    int c1 = 0, c2 = 0;
    int cur_g = batch[n0];
    for (int n = n0; n < n1; ++n) {
        int g = batch[n];
        if (g != cur_g) {
            if (c1) {
                atomicAdd(&pool[(0 * GG + cur_g) * 64 + lane], acc1);
                if (lane == 0) atomicAdd(&cnt[0 * GG + cur_g], (float)c1);
            }
            if (c2) {
                atomicAdd(&pool[(1 * GG + cur_g) * 64 + lane], acc2);
                if (lane == 0) atomicAdd(&cnt[1 * GG + cur_g], (float)c2);
            }
            acc1 = acc2 = 0.f;
            c1 = c2 = 0;
            cur_g = g;
        }
        int t = ntype[n];
        if (t == 1) { acc1 += h[n * 64 + lane]; c1++; }
        else if (t == 2) { acc2 += h[n * 64 + lane]; c2++; }
    }
    if (c1) {
        atomicAdd(&pool[(0 * GG + cur_g) * 64 + lane], acc1);
        if (lane == 0) atomicAdd(&cnt[0 * GG + cur_g], (float)c1);
    }
    if (c2) {
        atomicAdd(&pool[(1 * GG + cur_g) * 64 + lane], acc2);
        if (lane == 0) atomicAdd(&cnt[1 * GG + cur_g], (float)c2);
    }
}

// ---- final MLP ----
__global__ __launch_bounds__(256) void mlp_kernel(const float* __restrict__ pool,
                                                  const float* __restrict__ cnt,
                                                  const float* __restrict__ w1,
                                                  const float* __restrict__ b1,
                                                  const float* __restrict__ w2,
                                                  const float* __restrict__ b2,
                                                  float* __restrict__ out) {
    __shared__ float ro[GG * 128];
    __shared__ float hid[GG * 64];
    int tid = threadIdx.x;
    for (int t = tid; t < GG * 128; t += 256) {
        int g = t >> 7;
        int j = t & 127;
        int part = j >> 6;
        float c = fmaxf(cnt[part * GG + g], 1.0f);
        ro[t] = pool[(part * GG + g) * 64 + (j & 63)] / c;
    }
    __syncthreads();
    for (int t = tid; t < GG * 64; t += 256) {
        int g = t >> 6;
        int i = t & 63;
        float s = b1[i];
        for (int j = 0; j < 128; j++) s = fmaf(ro[g * 128 + j], w1[i * 128 + j], s);
        hid[t] = fmaxf(s, 0.f);
    }
    __syncthreads();
    if (tid < GG) {
        float s = b2[0];
        for (int i = 0; i < 64; i++) s = fmaf(hid[tid * 64 + i], w2[i], s);
        out[tid] = s;
    }
}

extern "C" void kernel_launch(void* const* d_in, const int* in_sizes, int n_in,
                              void* d_out, int out_size, void* d_ws, size_t ws_size,
                              hipStream_t stream) {
    const float* x       = (const float*)d_in[0];
    const int*   ei      = (const int*)d_in[1];
    const int*   ntype   = (const int*)d_in[2];
    const float* eattr   = (const float*)d_in[3];
    const int*   batch   = (const int*)d_in[4];
    const float* sage_wl = (const float*)d_in[5];
    const float* sage_bl = (const float*)d_in[6];
    const float* sage_wr = (const float*)d_in[7];
    const float* mlp_w1  = (const float*)d_in[8];
    const float* mlp_b1  = (const float*)d_in[9];
    const float* mlp_w2  = (const float*)d_in[10];
    const float* mlp_b2  = (const float*)d_in[11];
    const float* gw[3]  = {(const float*)d_in[12], (const float*)d_in[18], (const float*)d_in[24]};
    const float* gas[3] = {(const float*)d_in[13], (const float*)d_in[19], (const float*)d_in[25]};
    const float* gad[3] = {(const float*)d_in[14], (const float*)d_in[20], (const float*)d_in[26]};
    const float* gwe[3] = {(const float*)d_in[15], (const float*)d_in[21], (const float*)d_in[27]};
    const float* gae[3] = {(const float*)d_in[16], (const float*)d_in[22], (const float*)d_in[28]};
    const float* gb[3]  = {(const float*)d_in[17], (const float*)d_in[23], (const float*)d_in[29]};

    char* base = (char*)d_ws;
    size_t o = 0;
    auto alloc = [&](size_t bytes) -> char* {
        char* p = base + o;
        o = (o + bytes + 255) & ~(size_t)255;
        return p;
    };
    int*   deg     = (int*)  alloc(NN * 4);
    float* esum    = (float*)alloc(NN * 4);
    float* mean_e  = (float*)alloc(NN * 4);
    float* inv_deg = (float*)alloc(NN * 4);
    int*   row_off = (int*)  alloc((NN + 1) * 4);
    int*   pos     = (int*)  alloc(NN * 4);
    int*   csr_src = (int*)  alloc((size_t)EE * 4);
    float* csr_e   = (float*)alloc((size_t)EE * 4);
    float* xl      = (float*)alloc((size_t)NN * 64 * 4);
    float* xr      = (float*)alloc((size_t)NN * 64 * 4);
    float* hA      = (float*)alloc((size_t)NN * 64 * 4);
    float* hB      = (float*)alloc((size_t)NN * 64 * 4);
    float* hproj   = (float*)alloc((size_t)NN * 128 * 4);
    float* sval    = (float*)alloc((size_t)NN * 2 * 4);
    float* dval    = (float*)alloc((size_t)NN * 2 * 4);
    float* wt      = (float*)alloc(256 * 128 * 4);
    float* wtg     = (float*)alloc(64 * 128 * 4);
    float* pools   = (float*)alloc(2 * GG * 64 * 4);
    float* cnt     = (float*)alloc(2 * GG * 4);

    hipMemsetAsync(deg, 0, NN * 4, stream);
    hipMemsetAsync(esum, 0, NN * 4, stream);
    hipMemsetAsync(pools, 0, 2 * GG * 64 * 4, stream);
    hipMemsetAsync(cnt, 0, 2 * GG * 4, stream);

    deg_kernel<<<EE / 256, 256, 0, stream>>>(ei, eattr, deg, esum);
    scan_kernel<<<1, 1024, 0, stream>>>(deg, esum, row_off, pos, mean_e, inv_deg);
    fill_kernel<<<EE / 256, 256, 0, stream>>>(ei, eattr, pos, csr_src, csr_e);

    transpose2_kernel<<<256, 128, 0, stream>>>(sage_wl, sage_wr, wt);
    sage_mm_kernel<<<NN / NPB, 128, 0, stream>>>(x, wt, xl, xr);
    sage_agg_kernel<<<NN / 4, 256, 0, stream>>>(xl, xr, sage_bl, inv_deg, row_off, csr_src, hA);

    float* hin = hA;
    float* hout = hB;
    for (int L = 0; L < 3; ++L) {
        int H = (L == 2) ? 1 : 2;
        int H64 = H * 64;
        transpose_gat_kernel<<<64, 128, 0, stream>>>(gw[L], wtg, H64);
        proj_mm_kernel<<<NN / NPB, 128, 0, stream>>>(hin, wtg, hproj, H64);
        attval_kernel<<<NN / 4, 256, 0, stream>>>(hproj, gas[L], gad[L], sval, dval, H);
        gat_kernel<<<NN / 4, 256, 0, stream>>>(hproj, sval, dval, gwe[L], gae[L], gb[L],
                                               mean_e, row_off, csr_src, csr_e, hout, H);
        float* tmp = hin; hin = hout; hout = tmp;
    }
    // final features now in hin
    pool_kernel<<<128, 256, 0, stream>>>(hin, ntype, batch, pools, cnt);
    mlp_kernel<<<1, 256, 0, stream>>>(pools, cnt, mlp_w1, mlp_b1, mlp_w2, mlp_b2, (float*)d_out);
}

// Round 3
// 754.949 us; speedup vs baseline: 1.6806x; 1.4590x over previous
//
#include <hip/hip_runtime.h>
#include <hip/hip_bf16.h>

#define NN 50000
#define EE 800000
#define GG 16
#define IN_DIM 256
#define HID 64
#define NEG 0.2f
#define NPB 16

__device__ inline float wred_sum(float v) {
    for (int o = 32; o > 0; o >>= 1) v += __shfl_xor(v, o, 64);
    return v;
}
__device__ inline float wred_max(float v) {
    for (int o = 32; o > 0; o >>= 1) v = fmaxf(v, __shfl_xor(v, o, 64));
    return v;
}
// sum float4 across the 4 slot groups (lanes differing in bits 4,5)
__device__ inline void slot_reduce4(float4& a) {
    a.x += __shfl_xor(a.x, 16, 64); a.y += __shfl_xor(a.y, 16, 64);
    a.z += __shfl_xor(a.z, 16, 64); a.w += __shfl_xor(a.w, 16, 64);
    a.x += __shfl_xor(a.x, 32, 64); a.y += __shfl_xor(a.y, 32, 64);
    a.z += __shfl_xor(a.z, 32, 64); a.w += __shfl_xor(a.w, 32, 64);
}

__device__ inline float lrelu(float a) { return a > 0.f ? a : NEG * a; }

// ---- degree + edge_attr sum per dst ----
__global__ __launch_bounds__(256) void deg_kernel(const int* __restrict__ ei,
                                                  const float* __restrict__ eattr,
                                                  int* __restrict__ deg,
                                                  float* __restrict__ esum) {
    int e = blockIdx.x * 256 + threadIdx.x;
    if (e >= EE) return;
    int d = ei[EE + e];
    atomicAdd(&deg[d], 1);
    atomicAdd(&esum[d], eattr[e]);
}

// ---- single-block exclusive scan over deg; also mean_e, inv_deg, pos ----
__global__ __launch_bounds__(1024) void scan_kernel(const int* __restrict__ deg,
                                                    const float* __restrict__ esum,
                                                    int* __restrict__ row_off,
                                                    int* __restrict__ pos,
                                                    float* __restrict__ mean_e,
                                                    float* __restrict__ inv_deg) {
    __shared__ int buf[1024];
    __shared__ int carry;
    if (threadIdx.x == 0) carry = 0;
    __syncthreads();
    for (int base = 0; base < NN; base += 1024) {
        int i = base + threadIdx.x;
        int v = (i < NN) ? deg[i] : 0;
        buf[threadIdx.x] = v;
        __syncthreads();
        for (int ofs = 1; ofs < 1024; ofs <<= 1) {
            int t = (threadIdx.x >= ofs) ? buf[threadIdx.x - ofs] : 0;
            __syncthreads();
            buf[threadIdx.x] += t;
            __syncthreads();
        }
        int incl = buf[threadIdx.x];
        int excl = incl - v;
        if (i < NN) {
            int ro = carry + excl;
            row_off[i] = ro;
            pos[i] = ro;
            float idg = 1.0f / fmaxf((float)v, 1.0f);
            inv_deg[i] = idg;
            mean_e[i] = esum[i] * idg;
        }
        __syncthreads();
        if (threadIdx.x == 1023) carry += incl;
        __syncthreads();
    }
    if (threadIdx.x == 0) row_off[NN] = carry;
}

// ---- fill CSR buckets ----
__global__ __launch_bounds__(256) void fill_kernel(const int* __restrict__ ei,
                                                   const float* __restrict__ eattr,
                                                   int* __restrict__ pos,
                                                   int* __restrict__ csr_src,
                                                   float* __restrict__ csr_e) {
    int e = blockIdx.x * 256 + threadIdx.x;
    if (e >= EE) return;
    int d = ei[EE + e];
    int p = atomicAdd(&pos[d], 1);
    csr_src[p] = ei[e];
    csr_e[p] = eattr[e];
}

// ---- transpose+pack sage weights: wtp[(k>>2)*512 + j*4 + (k&3)] = [wl|wr][j][k] ----
__global__ void transpose2_kernel(const float* __restrict__ wl,
                                  const float* __restrict__ wr,
                                  float* __restrict__ wtp) {
    int k = blockIdx.x;      // 0..255
    int j = threadIdx.x;     // 0..127
    float v = (j < 64) ? wl[j * 256 + k] : wr[(j - 64) * 256 + k];
    wtp[(k >> 2) * 512 + j * 4 + (k & 3)] = v;
}

// ---- transpose+pack gat weight: wtgp[(k>>2)*(H64*4) + j*4 + (k&3)] = w[j][k] ----
__global__ void transpose_gat_kernel(const float* __restrict__ w,
                                     float* __restrict__ wtgp, int H64) {
    int k = blockIdx.x;   // 0..63
    int j = threadIdx.x;  // 0..127
    if (j < H64) wtgp[(k >> 2) * (H64 * 4) + j * 4 + (k & 3)] = w[j * 64 + k];
}

// ---- x @ [wl|wr].T : N x 256 -> N x 128 (xl, xr) ----
__global__ __launch_bounds__(128) void sage_mm_kernel(const float* __restrict__ x,
                                                      const float* __restrict__ wtp,
                                                      float* __restrict__ xl,
                                                      float* __restrict__ xr) {
    __shared__ float xs[NPB * 256];
    int node0 = blockIdx.x * NPB;
    for (int t = threadIdx.x; t < NPB * 256; t += 128)
        xs[t] = x[node0 * 256 + t];
    __syncthreads();
    int j = threadIdx.x;
    float acc[NPB];
#pragma unroll
    for (int n = 0; n < NPB; n++) acc[n] = 0.f;
    for (int k = 0; k < 256; k += 4) {
        const float4 wv = *(const float4*)&wtp[(k >> 2) * 512 + j * 4];
#pragma unroll
        for (int n = 0; n < NPB; n++) {
            const float4 xv = *(const float4*)&xs[n * 256 + k];
            acc[n] = fmaf(xv.x, wv.x, acc[n]);
            acc[n] = fmaf(xv.y, wv.y, acc[n]);
            acc[n] = fmaf(xv.z, wv.z, acc[n]);
            acc[n] = fmaf(xv.w, wv.w, acc[n]);
        }
    }
    for (int n = 0; n < NPB; n++) {
        int node = node0 + n;
        if (j < 64) xl[node * 64 + j] = acc[n];
        else        xr[node * 64 + (j - 64)] = acc[n];
    }
}

// ---- h @ W.T for GAT (+fused sval/dval attention scalars) ----
__global__ __launch_bounds__(128) void proj_mm_kernel(const float* __restrict__ hin,
                                                      const float* __restrict__ wtgp,
                                                      const float* __restrict__ a_s,
                                                      const float* __restrict__ a_d,
                                                      float* __restrict__ hproj,
                                                      float* __restrict__ sval,
                                                      float* __restrict__ dval, int H) {
    int H64 = H * 64;
    __shared__ float xs[NPB * 64];
    int node0 = blockIdx.x * NPB;
    for (int t = threadIdx.x; t < NPB * 64; t += 128)
        xs[t] = hin[node0 * 64 + t];
    __syncthreads();
    int j = threadIdx.x;
    if (j >= H64) return;           // whole-wave uniform (H64 is 64 or 128)
    int h = j >> 6;
    int lane = j & 63;
    float acc[NPB];
#pragma unroll
    for (int n = 0; n < NPB; n++) acc[n] = 0.f;
    for (int k = 0; k < 64; k += 4) {
        const float4 wv = *(const float4*)&wtgp[(k >> 2) * (H64 * 4) + j * 4];
#pragma unroll
        for (int n = 0; n < NPB; n++) {
            const float4 xv = *(const float4*)&xs[n * 64 + k];
            acc[n] = fmaf(xv.x, wv.x, acc[n]);
            acc[n] = fmaf(xv.y, wv.y, acc[n]);
            acc[n] = fmaf(xv.z, wv.z, acc[n]);
            acc[n] = fmaf(xv.w, wv.w, acc[n]);
        }
    }
    for (int n = 0; n < NPB; n++)
        hproj[(node0 + n) * H64 + j] = acc[n];
    // fused attval: per-node per-head scalars
    float as = a_s[j];
    float ad = a_d[j];
    for (int n = 0; n < NPB; n++) {
        float sv = wred_sum(acc[n] * as);
        float dv = wred_sum(acc[n] * ad);
        if (lane == 0) {
            sval[(node0 + n) * H + h] = sv;
            dval[(node0 + n) * H + h] = dv;
        }
    }
}

// ---- SAGE aggregation + combine + relu (4 edges in flight via slot layout) ----
__global__ __launch_bounds__(256) void sage_agg_kernel(const float* __restrict__ xl,
                                                       const float* __restrict__ xr,
                                                       const float* __restrict__ bl,
                                                       const float* __restrict__ inv_deg,
                                                       const int* __restrict__ row_off,
                                                       const int* __restrict__ csr_src,
                                                       float* __restrict__ hout) {
    int wid = blockIdx.x * 4 + (threadIdx.x >> 6);
    int lane = threadIdx.x & 63;
    if (wid >= NN) return;
    int slot = lane >> 4;
    int c4 = lane & 15;
    int r0 = row_off[wid], r1 = row_off[wid + 1];
    float4 acc = make_float4(0.f, 0.f, 0.f, 0.f);
    for (int idx = r0 + slot; idx < r1; idx += 4) {
        int s = csr_src[idx];
        const float4 hp = *(const float4*)&xl[(size_t)s * 64 + c4 * 4];
        acc.x += hp.x; acc.y += hp.y; acc.z += hp.z; acc.w += hp.w;
    }
    slot_reduce4(acc);
    if (slot == 0) {
        float idg = inv_deg[wid];
        const float4 b4 = *(const float4*)&bl[c4 * 4];
        const float4 xr4 = *(const float4*)&xr[(size_t)wid * 64 + c4 * 4];
        float4 v;
        v.x = fmaxf(acc.x * idg + b4.x + xr4.x, 0.f);
        v.y = fmaxf(acc.y * idg + b4.y + xr4.y, 0.f);
        v.z = fmaxf(acc.z * idg + b4.z + xr4.z, 0.f);
        v.w = fmaxf(acc.w * idg + b4.w + xr4.w, 0.f);
        *(float4*)&hout[(size_t)wid * 64 + c4 * 4] = v;
    }
}

// ---- GAT: online softmax + 4-edge-slot weighted aggregate ----
__global__ __launch_bounds__(256) void gat_kernel(const float* __restrict__ hproj,
                                                  const float* __restrict__ sval,
                                                  const float* __restrict__ dval,
                                                  const float* __restrict__ we,
                                                  const float* __restrict__ ae,
                                                  const float* __restrict__ bias,
                                                  const float* __restrict__ mean_e,
                                                  const int* __restrict__ row_off,
                                                  const int* __restrict__ csr_src,
                                                  const float* __restrict__ csr_e,
                                                  float* __restrict__ hout, int H) {
    int wid = blockIdx.x * 4 + (threadIdx.x >> 6);
    int lane = threadIdx.x & 63;
    if (wid >= NN) return;
    int slot = lane >> 4;
    int c4 = lane & 15;
    int H64 = H * 64;
    int r0 = row_off[wid], r1 = row_off[wid + 1];
    float me = mean_e[wid];
    float4 acc = make_float4(0.f, 0.f, 0.f, 0.f);
    for (int h = 0; h < H; ++h) {
        float wedot = wred_sum(we[h * 64 + lane] * ae[h * 64 + lane]);
        float dv = dval[wid * H + h];
        float a_self = lrelu(sval[wid * H + h] + dv + me * wedot);
        // single pass: online max + denom, lane-strided
        float m_l = -INFINITY, den_l = 0.f;
        for (int idx = r0 + lane; idx < r1; idx += 64) {
            int s = csr_src[idx];
            float a = lrelu(sval[s * H + h] + dv + csr_e[idx] * wedot);
            float mn = fmaxf(m_l, a);
            den_l = den_l * __expf(m_l - mn) + __expf(a - mn);
            m_l = mn;
        }
        float m = fmaxf(wred_max(m_l), a_self);
        float den = wred_sum(den_l * __expf(m_l - m)) + __expf(a_self - m);
        float inv_den = 1.0f / den;
        // weighted gather: 4 edges in flight (one per slot), float4 per lane
        for (int idx = r0 + slot; idx < r1; idx += 4) {
            int s = csr_src[idx];
            float a = lrelu(sval[s * H + h] + dv + csr_e[idx] * wedot);
            float c = __expf(a - m) * inv_den;
            const float4 hp = *(const float4*)&hproj[(size_t)s * H64 + h * 64 + c4 * 4];
            acc.x = fmaf(c, hp.x, acc.x);
            acc.y = fmaf(c, hp.y, acc.y);
            acc.z = fmaf(c, hp.z, acc.z);
            acc.w = fmaf(c, hp.w, acc.w);
        }
        if (slot == 0) {  // self-loop contribution
            float c = __expf(a_self - m) * inv_den;
            const float4 hp = *(const float4*)&hproj[(size_t)wid * H64 + h * 64 + c4 * 4];
            acc.x = fmaf(c, hp.x, acc.x);
            acc.y = fmaf(c, hp.y, acc.y);
            acc.z = fmaf(c, hp.z, acc.z);
            acc.w = fmaf(c, hp.w, acc.w);
        }
    }
    slot_reduce4(acc);
    if (slot == 0) {
        float invH = 1.0f / (float)H;
        const float4 b4 = *(const float4*)&bias[c4 * 4];
        float4 v;
        v.x = fmaxf(acc.x * invH + b4.x, 0.f);
        v.y = fmaxf(acc.y * invH + b4.y, 0.f);
        v.z = fmaxf(acc.z * invH + b4.z, 0.f);
        v.w = fmaxf(acc.w * invH + b4.w, 0.f);
        *(float4*)&hout[(size_t)wid * 64 + c4 * 4] = v;
    }
}

// ---- masked mean pool: batch sorted -> register accumulate, flush on boundary ----
__global__ __launch_bounds__(256) void pool_kernel(const float* __restrict__ h,
                                                   const int* __restrict__ ntype,
                                                   const int* __restrict__ batch,
                                                   float* __restrict__ pool,
                                                   float* __restrict__ cnt) {
    int nwaves = gridDim.x * 4;
    int wid = blockIdx.x * 4 + (threadIdx.x >> 6);
    int lane = threadIdx.x & 63;
    int chunk = (NN + nwaves - 1) / nwaves;
    int n0 = wid * chunk;
    int n1 = min(n0 + chunk, NN);
    if (n0 >= NN) return;
    float acc1 = 0.f, acc2 = 0.f;
    int c1 = 0, c2 = 0;
    int cur_g = batch[n0];
    for (int n = n0; n < n1; ++n) {
        int g = batch[n];
        if (g != cur_g) {
            if (c1) {
                atomicAdd(&pool[(0 * GG + cur_g) * 64 + lane], acc1);
                if (lane == 0) atomicAdd(&cnt[0 * GG + cur_g], (float)c1);
            }
            if (c2) {
                atomicAdd(&pool[(1 * GG + cur_g) * 64 + lane], acc2);
                if (lane == 0) atomicAdd(&cnt[1 * GG + cur_g], (float)c2);
            }
            acc1 = acc2 = 0.f;
            c1 = c2 = 0;
            cur_g = g;
        }
        int t = ntype[n];
        if (t == 1) { acc1 += h[n * 64 + lane]; c1++; }
        else if (t == 2) { acc2 += h[n * 64 + lane]; c2++; }
    }
    if (c1) {
        atomicAdd(&pool[(0 * GG + cur_g) * 64 + lane], acc1);
        if (lane == 0) atomicAdd(&cnt[0 * GG + cur_g], (float)c1);
    }
    if (c2) {
        atomicAdd(&pool[(1 * GG + cur_g) * 64 + lane], acc2);
        if (lane == 0) atomicAdd(&cnt[1 * GG + cur_g], (float)c2);
    }
}

// ---- final MLP ----
__global__ __launch_bounds__(256) void mlp_kernel(const float* __restrict__ pool,
                                                  const float* __restrict__ cnt,
                                                  const float* __restrict__ w1,
                                                  const float* __restrict__ b1,
                                                  const float* __restrict__ w2,
                                                  const float* __restrict__ b2,
                                                  float* __restrict__ out) {
    __shared__ float ro[GG * 128];
    __shared__ float hid[GG * 64];
    int tid = threadIdx.x;
    for (int t = tid; t < GG * 128; t += 256) {
        int g = t >> 7;
        int j = t & 127;
        int part = j >> 6;
        float c = fmaxf(cnt[part * GG + g], 1.0f);
        ro[t] = pool[(part * GG + g) * 64 + (j & 63)] / c;
    }
    __syncthreads();
    for (int t = tid; t < GG * 64; t += 256) {
        int g = t >> 6;
        int i = t & 63;
        float s = b1[i];
        for (int j = 0; j < 128; j++) s = fmaf(ro[g * 128 + j], w1[i * 128 + j], s);
        hid[t] = fmaxf(s, 0.f);
    }
    __syncthreads();
    if (tid < GG) {
        float s = b2[0];
        for (int i = 0; i < 64; i++) s = fmaf(hid[tid * 64 + i], w2[i], s);
        out[tid] = s;
    }
}

extern "C" void kernel_launch(void* const* d_in, const int* in_sizes, int n_in,
                              void* d_out, int out_size, void* d_ws, size_t ws_size,
                              hipStream_t stream) {
    const float* x       = (const float*)d_in[0];
    const int*   ei      = (const int*)d_in[1];
    const int*   ntype   = (const int*)d_in[2];
    const float* eattr   = (const float*)d_in[3];
    const int*   batch   = (const int*)d_in[4];
    const float* sage_wl = (const float*)d_in[5];
    const float* sage_bl = (const float*)d_in[6];
    const float* sage_wr = (const float*)d_in[7];
    const float* mlp_w1  = (const float*)d_in[8];
    const float* mlp_b1  = (const float*)d_in[9];
    const float* mlp_w2  = (const float*)d_in[10];
    const float* mlp_b2  = (const float*)d_in[11];
    const float* gw[3]  = {(const float*)d_in[12], (const float*)d_in[18], (const float*)d_in[24]};
    const float* gas[3] = {(const float*)d_in[13], (const float*)d_in[19], (const float*)d_in[25]};
    const float* gad[3] = {(const float*)d_in[14], (const float*)d_in[20], (const float*)d_in[26]};
    const float* gwe[3] = {(const float*)d_in[15], (const float*)d_in[21], (const float*)d_in[27]};
    const float* gae[3] = {(const float*)d_in[16], (const float*)d_in[22], (const float*)d_in[28]};
    const float* gb[3]  = {(const float*)d_in[17], (const float*)d_in[23], (const float*)d_in[29]};

    char* base = (char*)d_ws;
    size_t o = 0;
    auto alloc = [&](size_t bytes) -> char* {
        char* p = base + o;
        o = (o + bytes + 255) & ~(size_t)255;
        return p;
    };
    int*   deg     = (int*)  alloc(NN * 4);
    float* esum    = (float*)alloc(NN * 4);
    float* mean_e  = (float*)alloc(NN * 4);
    float* inv_deg = (float*)alloc(NN * 4);
    int*   row_off = (int*)  alloc((NN + 1) * 4);
    int*   pos     = (int*)  alloc(NN * 4);
    int*   csr_src = (int*)  alloc((size_t)EE * 4);
    float* csr_e   = (float*)alloc((size_t)EE * 4);
    float* xl      = (float*)alloc((size_t)NN * 64 * 4);
    float* xr      = (float*)alloc((size_t)NN * 64 * 4);
    float* hA      = (float*)alloc((size_t)NN * 64 * 4);
    float* hB      = (float*)alloc((size_t)NN * 64 * 4);
    float* hproj   = (float*)alloc((size_t)NN * 128 * 4);
    float* sval    = (float*)alloc((size_t)NN * 2 * 4);
    float* dval    = (float*)alloc((size_t)NN * 2 * 4);
    float* wt      = (float*)alloc(256 * 128 * 4);
    float* wtg     = (float*)alloc(64 * 128 * 4);
    float* pools   = (float*)alloc(2 * GG * 64 * 4);
    float* cnt     = (float*)alloc(2 * GG * 4);

    hipMemsetAsync(deg, 0, NN * 4, stream);
    hipMemsetAsync(esum, 0, NN * 4, stream);
    hipMemsetAsync(pools, 0, 2 * GG * 64 * 4, stream);
    hipMemsetAsync(cnt, 0, 2 * GG * 4, stream);

    deg_kernel<<<EE / 256, 256, 0, stream>>>(ei, eattr, deg, esum);
    scan_kernel<<<1, 1024, 0, stream>>>(deg, esum, row_off, pos, mean_e, inv_deg);
    fill_kernel<<<EE / 256, 256, 0, stream>>>(ei, eattr, pos, csr_src, csr_e);

    transpose2_kernel<<<256, 128, 0, stream>>>(sage_wl, sage_wr, wt);
    sage_mm_kernel<<<NN / NPB, 128, 0, stream>>>(x, wt, xl, xr);
    sage_agg_kernel<<<NN / 4, 256, 0, stream>>>(xl, xr, sage_bl, inv_deg, row_off, csr_src, hA);

    float* hin = hA;
    float* hout = hB;
    for (int L = 0; L < 3; ++L) {
        int H = (L == 2) ? 1 : 2;
        int H64 = H * 64;
        transpose_gat_kernel<<<64, 128, 0, stream>>>(gw[L], wtg, H64);
        proj_mm_kernel<<<NN / NPB, 128, 0, stream>>>(hin, wtg, gas[L], gad[L],
                                                     hproj, sval, dval, H);
        gat_kernel<<<NN / 4, 256, 0, stream>>>(hproj, sval, dval, gwe[L], gae[L], gb[L],
                                               mean_e, row_off, csr_src, csr_e, hout, H);
        float* tmp = hin; hin = hout; hout = tmp;
    }
    // final features now in hin
    pool_kernel<<<512, 256, 0, stream>>>(hin, ntype, batch, pools, cnt);
    mlp_kernel<<<1, 256, 0, stream>>>(pools, cnt, mlp_w1, mlp_b1, mlp_w2, mlp_b2, (float*)d_out);
}

// Round 4
// 739.965 us; speedup vs baseline: 1.7147x; 1.0202x over previous
//
#include <hip/hip_runtime.h>
#include <hip/hip_bf16.h>

#define NN 50000
#define EE 800000
#define GG 16
#define IN_DIM 256
#define HID 64
#define NEG 0.2f
#define SCAN_NB 49   // ceil(50000/1024)
#define SMT 40       // nodes per matmul block (50000 = 1250*40)

__device__ inline float wred_sum(float v) {
    for (int o = 32; o > 0; o >>= 1) v += __shfl_xor(v, o, 64);
    return v;
}
__device__ inline float wred_max(float v) {
    for (int o = 32; o > 0; o >>= 1) v = fmaxf(v, __shfl_xor(v, o, 64));
    return v;
}
// sum float4 across the 4 slot groups (lanes differing in bits 4,5)
__device__ inline void slot_reduce4(float4& a) {
    a.x += __shfl_xor(a.x, 16, 64); a.y += __shfl_xor(a.y, 16, 64);
    a.z += __shfl_xor(a.z, 16, 64); a.w += __shfl_xor(a.w, 16, 64);
    a.x += __shfl_xor(a.x, 32, 64); a.y += __shfl_xor(a.y, 32, 64);
    a.z += __shfl_xor(a.z, 32, 64); a.w += __shfl_xor(a.w, 32, 64);
}

__device__ inline float lrelu(float a) { return a > 0.f ? a : NEG * a; }

// ---- degree + edge_attr sum per dst ----
__global__ __launch_bounds__(256) void deg_kernel(const int* __restrict__ ei,
                                                  const float* __restrict__ eattr,
                                                  int* __restrict__ deg,
                                                  float* __restrict__ esum) {
    int e = blockIdx.x * 256 + threadIdx.x;
    if (e >= EE) return;
    int d = ei[EE + e];
    atomicAdd(&deg[d], 1);
    atomicAdd(&esum[d], eattr[e]);
}

// ---- scan stage 1: per-block exclusive scan of deg, block totals ----
__global__ __launch_bounds__(1024) void scan1_kernel(const int* __restrict__ deg,
                                                     int* __restrict__ row_off,
                                                     int* __restrict__ bsum) {
    __shared__ int buf[1024];
    int b = blockIdx.x;
    int i = b * 1024 + threadIdx.x;
    int v = (i < NN) ? deg[i] : 0;
    buf[threadIdx.x] = v;
    __syncthreads();
    for (int ofs = 1; ofs < 1024; ofs <<= 1) {
        int t = (threadIdx.x >= ofs) ? buf[threadIdx.x - ofs] : 0;
        __syncthreads();
        buf[threadIdx.x] += t;
        __syncthreads();
    }
    if (i < NN) row_off[i] = buf[threadIdx.x] - v;   // local exclusive
    if (threadIdx.x == 1023) bsum[b] = buf[1023];
}

// ---- scan stage 2: single-wave scan of block totals ----
__global__ __launch_bounds__(64) void scan2_kernel(const int* __restrict__ bsum,
                                                   int* __restrict__ boff,
                                                   int* __restrict__ row_off) {
    int l = threadIdx.x;
    int v = (l < SCAN_NB) ? bsum[l] : 0;
    int incl = v;
    for (int ofs = 1; ofs < 64; ofs <<= 1) {
        int t = __shfl_up(incl, ofs, 64);
        if (l >= ofs) incl += t;
    }
    if (l < SCAN_NB) boff[l] = incl - v;
    if (l == 63) row_off[NN] = incl;
}

// ---- scan stage 3: apply block offsets, derive pos/inv_deg/mean_e ----
__global__ __launch_bounds__(1024) void scan3_kernel(const int* __restrict__ deg,
                                                     const float* __restrict__ esum,
                                                     const int* __restrict__ boff,
                                                     int* __restrict__ row_off,
                                                     int* __restrict__ pos,
                                                     float* __restrict__ mean_e,
                                                     float* __restrict__ inv_deg) {
    int b = blockIdx.x;
    int i = b * 1024 + threadIdx.x;
    if (i >= NN) return;
    int ro = row_off[i] + boff[b];
    row_off[i] = ro;
    pos[i] = ro;
    float idg = 1.0f / fmaxf((float)deg[i], 1.0f);
    inv_deg[i] = idg;
    mean_e[i] = esum[i] * idg;
}

// ---- fill CSR buckets ----
__global__ __launch_bounds__(256) void fill_kernel(const int* __restrict__ ei,
                                                   const float* __restrict__ eattr,
                                                   int* __restrict__ pos,
                                                   int* __restrict__ csr_src,
                                                   float* __restrict__ csr_e) {
    int e = blockIdx.x * 256 + threadIdx.x;
    if (e >= EE) return;
    int d = ei[EE + e];
    int p = atomicAdd(&pos[d], 1);
    csr_src[p] = ei[e];
    csr_e[p] = eattr[e];
}

// ---- transpose+pack sage weights: wtp[(k>>2)*512 + j*4 + (k&3)] = [wl|wr][j][k] ----
__global__ void transpose2_kernel(const float* __restrict__ wl,
                                  const float* __restrict__ wr,
                                  float* __restrict__ wtp) {
    int k = blockIdx.x;      // 0..255
    int j = threadIdx.x;     // 0..127
    float v = (j < 64) ? wl[j * 256 + k] : wr[(j - 64) * 256 + k];
    wtp[(k >> 2) * 512 + j * 4 + (k & 3)] = v;
}

// ---- transpose+pack gat weight: wtgp[(k>>2)*(H64*4) + j*4 + (k&3)] = w[j][k] ----
__global__ void transpose_gat_kernel(const float* __restrict__ w,
                                     float* __restrict__ wtgp, int H64) {
    int k = blockIdx.x;   // 0..63
    int j = threadIdx.x;  // 0..127
    if (j < H64) wtgp[(k >> 2) * (H64 * 4) + j * 4 + (k & 3)] = w[j * 64 + k];
}

// ---- x @ [wl|wr].T : N x 256 -> N x 128 (xl, xr); 2 cols/thread, 40 nodes/block ----
__global__ __launch_bounds__(256) void sage_mm_kernel(const float* __restrict__ x,
                                                      const float* __restrict__ wtp,
                                                      float* __restrict__ xl,
                                                      float* __restrict__ xr) {
    __shared__ float xs[SMT * 256];
    int node0 = blockIdx.x * SMT;
    const float4* x4 = (const float4*)(x + (size_t)node0 * 256);
    float4* xs4 = (float4*)xs;
    for (int t = threadIdx.x; t < SMT * 64; t += 256) xs4[t] = x4[t];
    __syncthreads();
    int jj = threadIdx.x & 63;
    int g = threadIdx.x >> 6;           // node group: 10 nodes each
    float accL[10], accR[10];
#pragma unroll
    for (int n = 0; n < 10; n++) { accL[n] = 0.f; accR[n] = 0.f; }
    for (int k4 = 0; k4 < 64; k4++) {
        const float4 wL = *(const float4*)&wtp[k4 * 512 + jj * 4];
        const float4 wR = *(const float4*)&wtp[k4 * 512 + (jj + 64) * 4];
#pragma unroll
        for (int n = 0; n < 10; n++) {
            const float4 xv = xs4[(g * 10 + n) * 64 + k4];
            accL[n] = fmaf(xv.x, wL.x, accL[n]);
            accL[n] = fmaf(xv.y, wL.y, accL[n]);
            accL[n] = fmaf(xv.z, wL.z, accL[n]);
            accL[n] = fmaf(xv.w, wL.w, accL[n]);
            accR[n] = fmaf(xv.x, wR.x, accR[n]);
            accR[n] = fmaf(xv.y, wR.y, accR[n]);
            accR[n] = fmaf(xv.z, wR.z, accR[n]);
            accR[n] = fmaf(xv.w, wR.w, accR[n]);
        }
    }
#pragma unroll
    for (int n = 0; n < 10; n++) {
        int node = node0 + g * 10 + n;
        xl[(size_t)node * 64 + jj] = accL[n];
        xr[(size_t)node * 64 + jj] = accR[n];
    }
}

// ---- h @ W.T for GAT (+fused sval/dval); lane=channel, H cols/thread ----
template <int H>
__global__ __launch_bounds__(256) void proj_mm_kernel(const float* __restrict__ hin,
                                                      const float* __restrict__ wtgp,
                                                      const float* __restrict__ a_s,
                                                      const float* __restrict__ a_d,
                                                      float* __restrict__ hproj,
                                                      float* __restrict__ sval,
                                                      float* __restrict__ dval) {
    __shared__ float xs[SMT * 64];
    int node0 = blockIdx.x * SMT;
    const float4* h4 = (const float4*)(hin + (size_t)node0 * 64);
    float4* xs4 = (float4*)xs;
    for (int t = threadIdx.x; t < SMT * 16; t += 256) xs4[t] = h4[t];
    __syncthreads();
    int jj = threadIdx.x & 63;
    int g = threadIdx.x >> 6;
    float acc[H][10];
#pragma unroll
    for (int h = 0; h < H; h++)
#pragma unroll
        for (int n = 0; n < 10; n++) acc[h][n] = 0.f;
    for (int k4 = 0; k4 < 16; k4++) {
        float4 wv[H];
#pragma unroll
        for (int h = 0; h < H; h++)
            wv[h] = *(const float4*)&wtgp[k4 * (H * 256) + (h * 64 + jj) * 4];
#pragma unroll
        for (int n = 0; n < 10; n++) {
            const float4 xv = xs4[(g * 10 + n) * 16 + k4];
#pragma unroll
            for (int h = 0; h < H; h++) {
                acc[h][n] = fmaf(xv.x, wv[h].x, acc[h][n]);
                acc[h][n] = fmaf(xv.y, wv[h].y, acc[h][n]);
                acc[h][n] = fmaf(xv.z, wv[h].z, acc[h][n]);
                acc[h][n] = fmaf(xv.w, wv[h].w, acc[h][n]);
            }
        }
    }
#pragma unroll
    for (int h = 0; h < H; h++) {
        float as = a_s[h * 64 + jj];
        float ad = a_d[h * 64 + jj];
#pragma unroll
        for (int n = 0; n < 10; n++) {
            int node = node0 + g * 10 + n;
            hproj[(size_t)node * (H * 64) + h * 64 + jj] = acc[h][n];
            float sv = wred_sum(acc[h][n] * as);
            float dv = wred_sum(acc[h][n] * ad);
            if (jj == 0) {
                sval[node * H + h] = sv;
                dval[node * H + h] = dv;
            }
        }
    }
}

// ---- SAGE aggregation + combine + relu (4 edges in flight via slot layout) ----
__global__ __launch_bounds__(256) void sage_agg_kernel(const float* __restrict__ xl,
                                                       const float* __restrict__ xr,
                                                       const float* __restrict__ bl,
                                                       const float* __restrict__ inv_deg,
                                                       const int* __restrict__ row_off,
                                                       const int* __restrict__ csr_src,
                                                       float* __restrict__ hout) {
    int wid = blockIdx.x * 4 + (threadIdx.x >> 6);
    int lane = threadIdx.x & 63;
    if (wid >= NN) return;
    int slot = lane >> 4;
    int c4 = lane & 15;
    int r0 = row_off[wid], r1 = row_off[wid + 1];
    float4 acc = make_float4(0.f, 0.f, 0.f, 0.f);
    for (int idx = r0 + slot; idx < r1; idx += 4) {
        int s = csr_src[idx];
        const float4 hp = *(const float4*)&xl[(size_t)s * 64 + c4 * 4];
        acc.x += hp.x; acc.y += hp.y; acc.z += hp.z; acc.w += hp.w;
    }
    slot_reduce4(acc);
    if (slot == 0) {
        float idg = inv_deg[wid];
        const float4 b4 = *(const float4*)&bl[c4 * 4];
        const float4 xr4 = *(const float4*)&xr[(size_t)wid * 64 + c4 * 4];
        float4 v;
        v.x = fmaxf(acc.x * idg + b4.x + xr4.x, 0.f);
        v.y = fmaxf(acc.y * idg + b4.y + xr4.y, 0.f);
        v.z = fmaxf(acc.z * idg + b4.z + xr4.z, 0.f);
        v.w = fmaxf(acc.w * idg + b4.w + xr4.w, 0.f);
        *(float4*)&hout[(size_t)wid * 64 + c4 * 4] = v;
    }
}

// ---- GAT: online softmax + 4-edge-slot weighted aggregate ----
__global__ __launch_bounds__(256) void gat_kernel(const float* __restrict__ hproj,
                                                  const float* __restrict__ sval,
                                                  const float* __restrict__ dval,
                                                  const float* __restrict__ we,
                                                  const float* __restrict__ ae,
                                                  const float* __restrict__ bias,
                                                  const float* __restrict__ mean_e,
                                                  const int* __restrict__ row_off,
                                                  const int* __restrict__ csr_src,
                                                  const float* __restrict__ csr_e,
                                                  float* __restrict__ hout, int H) {
    int wid = blockIdx.x * 4 + (threadIdx.x >> 6);
    int lane = threadIdx.x & 63;
    if (wid >= NN) return;
    int slot = lane >> 4;
    int c4 = lane & 15;
    int H64 = H * 64;
    int r0 = row_off[wid], r1 = row_off[wid + 1];
    float me = mean_e[wid];
    float4 acc = make_float4(0.f, 0.f, 0.f, 0.f);
    for (int h = 0; h < H; ++h) {
        float wedot = wred_sum(we[h * 64 + lane] * ae[h * 64 + lane]);
        float dv = dval[wid * H + h];
        float a_self = lrelu(sval[wid * H + h] + dv + me * wedot);
        // single pass: online max + denom, lane-strided
        float m_l = -INFINITY, den_l = 0.f;
        for (int idx = r0 + lane; idx < r1; idx += 64) {
            int s = csr_src[idx];
            float a = lrelu(sval[s * H + h] + dv + csr_e[idx] * wedot);
            float mn = fmaxf(m_l, a);
            den_l = den_l * __expf(m_l - mn) + __expf(a - mn);
            m_l = mn;
        }
        float m = fmaxf(wred_max(m_l), a_self);
        float den = wred_sum(den_l * __expf(m_l - m)) + __expf(a_self - m);
        float inv_den = 1.0f / den;
        // weighted gather: 4 edges in flight (one per slot), float4 per lane
        for (int idx = r0 + slot; idx < r1; idx += 4) {
            int s = csr_src[idx];
            float a = lrelu(sval[s * H + h] + dv + csr_e[idx] * wedot);
            float c = __expf(a - m) * inv_den;
            const float4 hp = *(const float4*)&hproj[(size_t)s * H64 + h * 64 + c4 * 4];
            acc.x = fmaf(c, hp.x, acc.x);
            acc.y = fmaf(c, hp.y, acc.y);
            acc.z = fmaf(c, hp.z, acc.z);
            acc.w = fmaf(c, hp.w, acc.w);
        }
        if (slot == 0) {  // self-loop contribution
            float c = __expf(a_self - m) * inv_den;
            const float4 hp = *(const float4*)&hproj[(size_t)wid * H64 + h * 64 + c4 * 4];
            acc.x = fmaf(c, hp.x, acc.x);
            acc.y = fmaf(c, hp.y, acc.y);
            acc.z = fmaf(c, hp.z, acc.z);
            acc.w = fmaf(c, hp.w, acc.w);
        }
    }
    slot_reduce4(acc);
    if (slot == 0) {
        float invH = 1.0f / (float)H;
        const float4 b4 = *(const float4*)&bias[c4 * 4];
        float4 v;
        v.x = fmaxf(acc.x * invH + b4.x, 0.f);
        v.y = fmaxf(acc.y * invH + b4.y, 0.f);
        v.z = fmaxf(acc.z * invH + b4.z, 0.f);
        v.w = fmaxf(acc.w * invH + b4.w, 0.f);
        *(float4*)&hout[(size_t)wid * 64 + c4 * 4] = v;
    }
}

// ---- masked mean pool: batch sorted -> register accumulate, flush on boundary ----
__global__ __launch_bounds__(256) void pool_kernel(const float* __restrict__ h,
                                                   const int* __restrict__ ntype,
                                                   const int* __restrict__ batch,
                                                   float* __restrict__ pool,
                                                   float* __restrict__ cnt) {
    int nwaves = gridDim.x * 4;
    int wid = blockIdx.x * 4 + (threadIdx.x >> 6);
    int lane = threadIdx.x & 63;
    int chunk = (NN + nwaves - 1) / nwaves;
    int n0 = wid * chunk;
    int n1 = min(n0 + chunk, NN);
    if (n0 >= NN) return;
    float acc1 = 0.f, acc2 = 0.f;
    int c1 = 0, c2 = 0;
    int cur_g = batch[n0];
    for (int n = n0; n < n1; ++n) {
        int g = batch[n];
        if (g != cur_g) {
            if (c1) {
                atomicAdd(&pool[(0 * GG + cur_g) * 64 + lane], acc1);
                if (lane == 0) atomicAdd(&cnt[0 * GG + cur_g], (float)c1);
            }
            if (c2) {
                atomicAdd(&pool[(1 * GG + cur_g) * 64 + lane], acc2);
                if (lane == 0) atomicAdd(&cnt[1 * GG + cur_g], (float)c2);
            }
            acc1 = acc2 = 0.f;
            c1 = c2 = 0;
            cur_g = g;
        }
        int t = ntype[n];
        if (t == 1) { acc1 += h[n * 64 + lane]; c1++; }
        else if (t == 2) { acc2 += h[n * 64 + lane]; c2++; }
    }
    if (c1) {
        atomicAdd(&pool[(0 * GG + cur_g) * 64 + lane], acc1);
        if (lane == 0) atomicAdd(&cnt[0 * GG + cur_g], (float)c1);
    }
    if (c2) {
        atomicAdd(&pool[(1 * GG + cur_g) * 64 + lane], acc2);
        if (lane == 0) atomicAdd(&cnt[1 * GG + cur_g], (float)c2);
    }
}

// ---- final MLP ----
__global__ __launch_bounds__(256) void mlp_kernel(const float* __restrict__ pool,
                                                  const float* __restrict__ cnt,
                                                  const float* __restrict__ w1,
                                                  const float* __restrict__ b1,
                                                  const float* __restrict__ w2,
                                                  const float* __restrict__ b2,
                                                  float* __restrict__ out) {
    __shared__ float ro[GG * 128];
    __shared__ float hid[GG * 64];
    int tid = threadIdx.x;
    for (int t = tid; t < GG * 128; t += 256) {
        int g = t >> 7;
        int j = t & 127;
        int part = j >> 6;
        float c = fmaxf(cnt[part * GG + g], 1.0f);
        ro[t] = pool[(part * GG + g) * 64 + (j & 63)] / c;
    }
    __syncthreads();
    for (int t = tid; t < GG * 64; t += 256) {
        int g = t >> 6;
        int i = t & 63;
        float s = b1[i];
        for (int j = 0; j < 128; j++) s = fmaf(ro[g * 128 + j], w1[i * 128 + j], s);
        hid[t] = fmaxf(s, 0.f);
    }
    __syncthreads();
    if (tid < GG) {
        float s = b2[0];
        for (int i = 0; i < 64; i++) s = fmaf(hid[tid * 64 + i], w2[i], s);
        out[tid] = s;
    }
}

extern "C" void kernel_launch(void* const* d_in, const int* in_sizes, int n_in,
                              void* d_out, int out_size, void* d_ws, size_t ws_size,
                              hipStream_t stream) {
    const float* x       = (const float*)d_in[0];
    const int*   ei      = (const int*)d_in[1];
    const int*   ntype   = (const int*)d_in[2];
    const float* eattr   = (const float*)d_in[3];
    const int*   batch   = (const int*)d_in[4];
    const float* sage_wl = (const float*)d_in[5];
    const float* sage_bl = (const float*)d_in[6];
    const float* sage_wr = (const float*)d_in[7];
    const float* mlp_w1  = (const float*)d_in[8];
    const float* mlp_b1  = (const float*)d_in[9];
    const float* mlp_w2  = (const float*)d_in[10];
    const float* mlp_b2  = (const float*)d_in[11];
    const float* gw[3]  = {(const float*)d_in[12], (const float*)d_in[18], (const float*)d_in[24]};
    const float* gas[3] = {(const float*)d_in[13], (const float*)d_in[19], (const float*)d_in[25]};
    const float* gad[3] = {(const float*)d_in[14], (const float*)d_in[20], (const float*)d_in[26]};
    const float* gwe[3] = {(const float*)d_in[15], (const float*)d_in[21], (const float*)d_in[27]};
    const float* gae[3] = {(const float*)d_in[16], (const float*)d_in[22], (const float*)d_in[28]};
    const float* gb[3]  = {(const float*)d_in[17], (const float*)d_in[23], (const float*)d_in[29]};

    char* base = (char*)d_ws;
    size_t o = 0;
    auto alloc = [&](size_t bytes) -> char* {
        char* p = base + o;
        o = (o + bytes + 255) & ~(size_t)255;
        return p;
    };
    int*   deg     = (int*)  alloc(NN * 4);
    float* esum    = (float*)alloc(NN * 4);
    float* mean_e  = (float*)alloc(NN * 4);
    float* inv_deg = (float*)alloc(NN * 4);
    int*   row_off = (int*)  alloc((NN + 1) * 4);
    int*   pos     = (int*)  alloc(NN * 4);
    int*   bsum    = (int*)  alloc(64 * 4);
    int*   boff    = (int*)  alloc(64 * 4);
    int*   csr_src = (int*)  alloc((size_t)EE * 4);
    float* csr_e   = (float*)alloc((size_t)EE * 4);
    float* xl      = (float*)alloc((size_t)NN * 64 * 4);
    float* xr      = (float*)alloc((size_t)NN * 64 * 4);
    float* hA      = (float*)alloc((size_t)NN * 64 * 4);
    float* hB      = (float*)alloc((size_t)NN * 64 * 4);
    float* hproj   = (float*)alloc((size_t)NN * 128 * 4);
    float* sval    = (float*)alloc((size_t)NN * 2 * 4);
    float* dval    = (float*)alloc((size_t)NN * 2 * 4);
    float* wt      = (float*)alloc(256 * 128 * 4);
    float* wtg     = (float*)alloc(64 * 128 * 4);
    float* pools   = (float*)alloc(2 * GG * 64 * 4);
    float* cnt     = (float*)alloc(2 * GG * 4);

    hipMemsetAsync(deg, 0, NN * 4, stream);
    hipMemsetAsync(esum, 0, NN * 4, stream);
    hipMemsetAsync(pools, 0, 2 * GG * 64 * 4, stream);
    hipMemsetAsync(cnt, 0, 2 * GG * 4, stream);

    deg_kernel<<<EE / 256, 256, 0, stream>>>(ei, eattr, deg, esum);
    scan1_kernel<<<SCAN_NB, 1024, 0, stream>>>(deg, row_off, bsum);
    scan2_kernel<<<1, 64, 0, stream>>>(bsum, boff, row_off);
    scan3_kernel<<<SCAN_NB, 1024, 0, stream>>>(deg, esum, boff, row_off, pos, mean_e, inv_deg);
    fill_kernel<<<EE / 256, 256, 0, stream>>>(ei, eattr, pos, csr_src, csr_e);

    transpose2_kernel<<<256, 128, 0, stream>>>(sage_wl, sage_wr, wt);
    sage_mm_kernel<<<NN / SMT, 256, 0, stream>>>(x, wt, xl, xr);
    sage_agg_kernel<<<NN / 4, 256, 0, stream>>>(xl, xr, sage_bl, inv_deg, row_off, csr_src, hA);

    float* hin = hA;
    float* hout = hB;
    for (int L = 0; L < 3; ++L) {
        int H = (L == 2) ? 1 : 2;
        int H64 = H * 64;
        transpose_gat_kernel<<<64, 128, 0, stream>>>(gw[L], wtg, H64);
        if (H == 2)
            proj_mm_kernel<2><<<NN / SMT, 256, 0, stream>>>(hin, wtg, gas[L], gad[L],
                                                            hproj, sval, dval);
        else
            proj_mm_kernel<1><<<NN / SMT, 256, 0, stream>>>(hin, wtg, gas[L], gad[L],
                                                            hproj, sval, dval);
        gat_kernel<<<NN / 4, 256, 0, stream>>>(hproj, sval, dval, gwe[L], gae[L], gb[L],
                                               mean_e, row_off, csr_src, csr_e, hout, H);
        float* tmp = hin; hin = hout; hout = tmp;
    }
    // final features now in hin
    pool_kernel<<<512, 256, 0, stream>>>(hin, ntype, batch, pools, cnt);
    mlp_kernel<<<1, 256, 0, stream>>>(pools, cnt, mlp_w1, mlp_b1, mlp_w2, mlp_b2, (float*)d_out);
}

// Round 5
// 622.002 us; speedup vs baseline: 2.0399x; 1.1897x over previous
//
#include <hip/hip_runtime.h>
#include <hip/hip_bf16.h>

#define NN 50000
#define EE 800000
#define GG 16
#define IN_DIM 256
#define HID 64
#define NEG 0.2f
#define SCAN_NB 49   // ceil(50000/1024)
#define SMT 40       // nodes per matmul block (50000 = 1250*40)

__device__ inline float wred_sum(float v) {
    for (int o = 32; o > 0; o >>= 1) v += __shfl_xor(v, o, 64);
    return v;
}
__device__ inline float wred_max(float v) {
    for (int o = 32; o > 0; o >>= 1) v = fmaxf(v, __shfl_xor(v, o, 64));
    return v;
}
// sum float4 across the 4 slot groups (lanes differing in bits 4,5)
__device__ inline void slot_reduce4(float4& a) {
    a.x += __shfl_xor(a.x, 16, 64); a.y += __shfl_xor(a.y, 16, 64);
    a.z += __shfl_xor(a.z, 16, 64); a.w += __shfl_xor(a.w, 16, 64);
    a.x += __shfl_xor(a.x, 32, 64); a.y += __shfl_xor(a.y, 32, 64);
    a.z += __shfl_xor(a.z, 32, 64); a.w += __shfl_xor(a.w, 32, 64);
}

__device__ inline float lrelu(float a) { return a > 0.f ? a : NEG * a; }

// ---- degree + edge_attr sum per dst ----
__global__ __launch_bounds__(256) void deg_kernel(const int* __restrict__ ei,
                                                  const float* __restrict__ eattr,
                                                  int* __restrict__ deg,
                                                  float* __restrict__ esum) {
    int e = blockIdx.x * 256 + threadIdx.x;
    if (e >= EE) return;
    int d = ei[EE + e];
    atomicAdd(&deg[d], 1);
    atomicAdd(&esum[d], eattr[e]);
}

// ---- scan stage 1: per-block exclusive scan of deg, block totals ----
__global__ __launch_bounds__(1024) void scan1_kernel(const int* __restrict__ deg,
                                                     int* __restrict__ row_off,
                                                     int* __restrict__ bsum) {
    __shared__ int buf[1024];
    int b = blockIdx.x;
    int i = b * 1024 + threadIdx.x;
    int v = (i < NN) ? deg[i] : 0;
    buf[threadIdx.x] = v;
    __syncthreads();
    for (int ofs = 1; ofs < 1024; ofs <<= 1) {
        int t = (threadIdx.x >= ofs) ? buf[threadIdx.x - ofs] : 0;
        __syncthreads();
        buf[threadIdx.x] += t;
        __syncthreads();
    }
    if (i < NN) row_off[i] = buf[threadIdx.x] - v;   // local exclusive
    if (threadIdx.x == 1023) bsum[b] = buf[1023];
}

// ---- scan stage 2: single-wave scan of block totals ----
__global__ __launch_bounds__(64) void scan2_kernel(const int* __restrict__ bsum,
                                                   int* __restrict__ boff,
                                                   int* __restrict__ row_off) {
    int l = threadIdx.x;
    int v = (l < SCAN_NB) ? bsum[l] : 0;
    int incl = v;
    for (int ofs = 1; ofs < 64; ofs <<= 1) {
        int t = __shfl_up(incl, ofs, 64);
        if (l >= ofs) incl += t;
    }
    if (l < SCAN_NB) boff[l] = incl - v;
    if (l == 63) row_off[NN] = incl;
}

// ---- scan stage 3: apply block offsets, derive pos/inv_deg/mean_e ----
__global__ __launch_bounds__(1024) void scan3_kernel(const int* __restrict__ deg,
                                                     const float* __restrict__ esum,
                                                     const int* __restrict__ boff,
                                                     int* __restrict__ row_off,
                                                     int* __restrict__ pos,
                                                     float* __restrict__ mean_e,
                                                     float* __restrict__ inv_deg) {
    int b = blockIdx.x;
    int i = b * 1024 + threadIdx.x;
    if (i >= NN) return;
    int ro = row_off[i] + boff[b];
    row_off[i] = ro;
    pos[i] = ro;
    float idg = 1.0f / fmaxf((float)deg[i], 1.0f);
    inv_deg[i] = idg;
    mean_e[i] = esum[i] * idg;
}

// ---- fill CSR buckets ----
__global__ __launch_bounds__(256) void fill_kernel(const int* __restrict__ ei,
                                                   const float* __restrict__ eattr,
                                                   int* __restrict__ pos,
                                                   int* __restrict__ csr_src,
                                                   float* __restrict__ csr_e) {
    int e = blockIdx.x * 256 + threadIdx.x;
    if (e >= EE) return;
    int d = ei[EE + e];
    int p = atomicAdd(&pos[d], 1);
    csr_src[p] = ei[e];
    csr_e[p] = eattr[e];
}

// ---- transpose+pack sage weights: wtp[(k>>2)*512 + j*4 + (k&3)] = [wl|wr][j][k] ----
__global__ void transpose2_kernel(const float* __restrict__ wl,
                                  const float* __restrict__ wr,
                                  float* __restrict__ wtp) {
    int k = blockIdx.x;      // 0..255
    int j = threadIdx.x;     // 0..127
    float v = (j < 64) ? wl[j * 256 + k] : wr[(j - 64) * 256 + k];
    wtp[(k >> 2) * 512 + j * 4 + (k & 3)] = v;
}

// ---- transpose+pack gat weight + fold attention vectors through W:
//      wtgp[(k>>2)*(H64*4) + j*4 + (k&3)] = w[j][k]
//      asw[h*64+k] = sum_c a_s[h*64+c] * w[(h*64+c)*64+k]   (and adw likewise)
//      wedot[h]    = sum_c we[h*64+c] * ae[h*64+c]
__global__ void transpose_gat_kernel(const float* __restrict__ w,
                                     const float* __restrict__ a_s,
                                     const float* __restrict__ a_d,
                                     const float* __restrict__ we,
                                     const float* __restrict__ ae,
                                     float* __restrict__ wtgp,
                                     float* __restrict__ asw,
                                     float* __restrict__ adw,
                                     float* __restrict__ wedot, int H64) {
    int k = blockIdx.x;   // 0..63
    int j = threadIdx.x;  // 0..127  (= h*64 + c)
    if (j >= H64) return;
    int h = j >> 6;
    int c = j & 63;
    float wv = w[j * 64 + k];
    wtgp[(k >> 2) * (H64 * 4) + j * 4 + (k & 3)] = wv;
    float sv = wred_sum(wv * a_s[j]);
    float dv = wred_sum(wv * a_d[j]);
    if (c == 0) {
        asw[h * 64 + k] = sv;
        adw[h * 64 + k] = dv;
    }
    if (k == 0) {
        float wd = wred_sum(we[j] * ae[j]);
        if (c == 0) wedot[h] = wd;
    }
}

// ---- x @ [wl|wr].T : N x 256 -> N x 128 (xl, xr); 2 cols/thread, 40 nodes/block ----
__global__ __launch_bounds__(256) void sage_mm_kernel(const float* __restrict__ x,
                                                      const float* __restrict__ wtp,
                                                      float* __restrict__ xl,
                                                      float* __restrict__ xr) {
    __shared__ float xs[SMT * 256];
    int node0 = blockIdx.x * SMT;
    const float4* x4 = (const float4*)(x + (size_t)node0 * 256);
    float4* xs4 = (float4*)xs;
    for (int t = threadIdx.x; t < SMT * 64; t += 256) xs4[t] = x4[t];
    __syncthreads();
    int jj = threadIdx.x & 63;
    int g = threadIdx.x >> 6;           // node group: 10 nodes each
    float accL[10], accR[10];
#pragma unroll
    for (int n = 0; n < 10; n++) { accL[n] = 0.f; accR[n] = 0.f; }
    for (int k4 = 0; k4 < 64; k4++) {
        const float4 wL = *(const float4*)&wtp[k4 * 512 + jj * 4];
        const float4 wR = *(const float4*)&wtp[k4 * 512 + (jj + 64) * 4];
#pragma unroll
        for (int n = 0; n < 10; n++) {
            const float4 xv = xs4[(g * 10 + n) * 64 + k4];
            accL[n] = fmaf(xv.x, wL.x, accL[n]);
            accL[n] = fmaf(xv.y, wL.y, accL[n]);
            accL[n] = fmaf(xv.z, wL.z, accL[n]);
            accL[n] = fmaf(xv.w, wL.w, accL[n]);
            accR[n] = fmaf(xv.x, wR.x, accR[n]);
            accR[n] = fmaf(xv.y, wR.y, accR[n]);
            accR[n] = fmaf(xv.z, wR.z, accR[n]);
            accR[n] = fmaf(xv.w, wR.w, accR[n]);
        }
    }
#pragma unroll
    for (int n = 0; n < 10; n++) {
        int node = node0 + g * 10 + n;
        xl[(size_t)node * 64 + jj] = accL[n];
        xr[(size_t)node * 64 + jj] = accR[n];
    }
}

// ---- h @ W.T for GAT: pure GEMM, no cross-lane epilogue ----
template <int H>
__global__ __launch_bounds__(256) void proj_mm_kernel(const float* __restrict__ hin,
                                                      const float* __restrict__ wtgp,
                                                      float* __restrict__ hproj) {
    __shared__ float xs[SMT * 64];
    int node0 = blockIdx.x * SMT;
    const float4* h4 = (const float4*)(hin + (size_t)node0 * 64);
    float4* xs4 = (float4*)xs;
    for (int t = threadIdx.x; t < SMT * 16; t += 256) xs4[t] = h4[t];
    __syncthreads();
    int jj = threadIdx.x & 63;
    int g = threadIdx.x >> 6;
    float acc[H][10];
#pragma unroll
    for (int h = 0; h < H; h++)
#pragma unroll
        for (int n = 0; n < 10; n++) acc[h][n] = 0.f;
#pragma unroll 4
    for (int k4 = 0; k4 < 16; k4++) {
        float4 wv[H];
#pragma unroll
        for (int h = 0; h < H; h++)
            wv[h] = *(const float4*)&wtgp[k4 * (H * 256) + (h * 64 + jj) * 4];
#pragma unroll
        for (int n = 0; n < 10; n++) {
            const float4 xv = xs4[(g * 10 + n) * 16 + k4];
#pragma unroll
            for (int h = 0; h < H; h++) {
                acc[h][n] = fmaf(xv.x, wv[h].x, acc[h][n]);
                acc[h][n] = fmaf(xv.y, wv[h].y, acc[h][n]);
                acc[h][n] = fmaf(xv.z, wv[h].z, acc[h][n]);
                acc[h][n] = fmaf(xv.w, wv[h].w, acc[h][n]);
            }
        }
    }
#pragma unroll
    for (int h = 0; h < H; h++)
#pragma unroll
        for (int n = 0; n < 10; n++)
            hproj[(size_t)(node0 + g * 10 + n) * (H * 64) + h * 64 + jj] = acc[h][n];
}

// ---- per-(node,head) attention scalars from hin @ asw / adw (wave per node) ----
__global__ __launch_bounds__(256) void attval_kernel(const float* __restrict__ hin,
                                                     const float* __restrict__ asw,
                                                     const float* __restrict__ adw,
                                                     float* __restrict__ sval,
                                                     float* __restrict__ dval, int H) {
    int wid = (blockIdx.x * 256 + threadIdx.x) >> 6;
    int lane = threadIdx.x & 63;
    if (wid >= NN) return;
    float hv = hin[(size_t)wid * 64 + lane];
    for (int h = 0; h < H; ++h) {
        float sv = wred_sum(hv * asw[h * 64 + lane]);
        float dv = wred_sum(hv * adw[h * 64 + lane]);
        if (lane == 0) {
            sval[wid * H + h] = sv;
            dval[wid * H + h] = dv;
        }
    }
}

// ---- SAGE aggregation + combine + relu (4 edges in flight via slot layout) ----
__global__ __launch_bounds__(256) void sage_agg_kernel(const float* __restrict__ xl,
                                                       const float* __restrict__ xr,
                                                       const float* __restrict__ bl,
                                                       const float* __restrict__ inv_deg,
                                                       const int* __restrict__ row_off,
                                                       const int* __restrict__ csr_src,
                                                       float* __restrict__ hout) {
    int wid = blockIdx.x * 4 + (threadIdx.x >> 6);
    int lane = threadIdx.x & 63;
    if (wid >= NN) return;
    int slot = lane >> 4;
    int c4 = lane & 15;
    int r0 = row_off[wid], r1 = row_off[wid + 1];
    float4 acc = make_float4(0.f, 0.f, 0.f, 0.f);
    for (int idx = r0 + slot; idx < r1; idx += 4) {
        int s = csr_src[idx];
        const float4 hp = *(const float4*)&xl[(size_t)s * 64 + c4 * 4];
        acc.x += hp.x; acc.y += hp.y; acc.z += hp.z; acc.w += hp.w;
    }
    slot_reduce4(acc);
    if (slot == 0) {
        float idg = inv_deg[wid];
        const float4 b4 = *(const float4*)&bl[c4 * 4];
        const float4 xr4 = *(const float4*)&xr[(size_t)wid * 64 + c4 * 4];
        float4 v;
        v.x = fmaxf(acc.x * idg + b4.x + xr4.x, 0.f);
        v.y = fmaxf(acc.y * idg + b4.y + xr4.y, 0.f);
        v.z = fmaxf(acc.z * idg + b4.z + xr4.z, 0.f);
        v.w = fmaxf(acc.w * idg + b4.w + xr4.w, 0.f);
        *(float4*)&hout[(size_t)wid * 64 + c4 * 4] = v;
    }
}

// ---- GAT: online softmax + 4-edge-slot weighted aggregate ----
__global__ __launch_bounds__(256) void gat_kernel(const float* __restrict__ hproj,
                                                  const float* __restrict__ sval,
                                                  const float* __restrict__ dval,
                                                  const float* __restrict__ wedot_buf,
                                                  const float* __restrict__ bias,
                                                  const float* __restrict__ mean_e,
                                                  const int* __restrict__ row_off,
                                                  const int* __restrict__ csr_src,
                                                  const float* __restrict__ csr_e,
                                                  float* __restrict__ hout, int H) {
    int wid = blockIdx.x * 4 + (threadIdx.x >> 6);
    int lane = threadIdx.x & 63;
    if (wid >= NN) return;
    int slot = lane >> 4;
    int c4 = lane & 15;
    int H64 = H * 64;
    int r0 = row_off[wid], r1 = row_off[wid + 1];
    float me = mean_e[wid];
    float4 acc = make_float4(0.f, 0.f, 0.f, 0.f);
    for (int h = 0; h < H; ++h) {
        float wedot = wedot_buf[h];
        float dv = dval[wid * H + h];
        float a_self = lrelu(sval[wid * H + h] + dv + me * wedot);
        // single pass: online max + denom, lane-strided
        float m_l = -INFINITY, den_l = 0.f;
        for (int idx = r0 + lane; idx < r1; idx += 64) {
            int s = csr_src[idx];
            float a = lrelu(sval[s * H + h] + dv + csr_e[idx] * wedot);
            float mn = fmaxf(m_l, a);
            den_l = den_l * __expf(m_l - mn) + __expf(a - mn);
            m_l = mn;
        }
        float m = fmaxf(wred_max(m_l), a_self);
        float den = wred_sum(den_l * __expf(m_l - m)) + __expf(a_self - m);
        float inv_den = 1.0f / den;
        // weighted gather: 4 edges in flight (one per slot), float4 per lane
        for (int idx = r0 + slot; idx < r1; idx += 4) {
            int s = csr_src[idx];
            float a = lrelu(sval[s * H + h] + dv + csr_e[idx] * wedot);
            float c = __expf(a - m) * inv_den;
            const float4 hp = *(const float4*)&hproj[(size_t)s * H64 + h * 64 + c4 * 4];
            acc.x = fmaf(c, hp.x, acc.x);
            acc.y = fmaf(c, hp.y, acc.y);
            acc.z = fmaf(c, hp.z, acc.z);
            acc.w = fmaf(c, hp.w, acc.w);
        }
        if (slot == 0) {  // self-loop contribution
            float c = __expf(a_self - m) * inv_den;
            const float4 hp = *(const float4*)&hproj[(size_t)wid * H64 + h * 64 + c4 * 4];
            acc.x = fmaf(c, hp.x, acc.x);
            acc.y = fmaf(c, hp.y, acc.y);
            acc.z = fmaf(c, hp.z, acc.z);
            acc.w = fmaf(c, hp.w, acc.w);
        }
    }
    slot_reduce4(acc);
    if (slot == 0) {
        float invH = 1.0f / (float)H;
        const float4 b4 = *(const float4*)&bias[c4 * 4];
        float4 v;
        v.x = fmaxf(acc.x * invH + b4.x, 0.f);
        v.y = fmaxf(acc.y * invH + b4.y, 0.f);
        v.z = fmaxf(acc.z * invH + b4.z, 0.f);
        v.w = fmaxf(acc.w * invH + b4.w, 0.f);
        *(float4*)&hout[(size_t)wid * 64 + c4 * 4] = v;
    }
}

// ---- masked mean pool: batch sorted -> register accumulate, flush on boundary ----
__global__ __launch_bounds__(256) void pool_kernel(const float* __restrict__ h,
                                                   const int* __restrict__ ntype,
                                                   const int* __restrict__ batch,
                                                   float* __restrict__ pool,
                                                   float* __restrict__ cnt) {
    int nwaves = gridDim.x * 4;
    int wid = blockIdx.x * 4 + (threadIdx.x >> 6);
    int lane = threadIdx.x & 63;
    int chunk = (NN + nwaves - 1) / nwaves;
    int n0 = wid * chunk;
    int n1 = min(n0 + chunk, NN);
    if (n0 >= NN) return;
    float acc1 = 0.f, acc2 = 0.f;
    int c1 = 0, c2 = 0;
    int cur_g = batch[n0];
    for (int n = n0; n < n1; ++n) {
        int g = batch[n];
        if (g != cur_g) {
            if (c1) {
                atomicAdd(&pool[(0 * GG + cur_g) * 64 + lane], acc1);
                if (lane == 0) atomicAdd(&cnt[0 * GG + cur_g], (float)c1);
            }
            if (c2) {
                atomicAdd(&pool[(1 * GG + cur_g) * 64 + lane], acc2);
                if (lane == 0) atomicAdd(&cnt[1 * GG + cur_g], (float)c2);
            }
            acc1 = acc2 = 0.f;
            c1 = c2 = 0;
            cur_g = g;
        }
        int t = ntype[n];
        if (t == 1) { acc1 += h[n * 64 + lane]; c1++; }
        else if (t == 2) { acc2 += h[n * 64 + lane]; c2++; }
    }
    if (c1) {
        atomicAdd(&pool[(0 * GG + cur_g) * 64 + lane], acc1);
        if (lane == 0) atomicAdd(&cnt[0 * GG + cur_g], (float)c1);
    }
    if (c2) {
        atomicAdd(&pool[(1 * GG + cur_g) * 64 + lane], acc2);
        if (lane == 0) atomicAdd(&cnt[1 * GG + cur_g], (float)c2);
    }
}

// ---- final MLP ----
__global__ __launch_bounds__(256) void mlp_kernel(const float* __restrict__ pool,
                                                  const float* __restrict__ cnt,
                                                  const float* __restrict__ w1,
                                                  const float* __restrict__ b1,
                                                  const float* __restrict__ w2,
                                                  const float* __restrict__ b2,
                                                  float* __restrict__ out) {
    __shared__ float ro[GG * 128];
    __shared__ float hid[GG * 64];
    int tid = threadIdx.x;
    for (int t = tid; t < GG * 128; t += 256) {
        int g = t >> 7;
        int j = t & 127;
        int part = j >> 6;
        float c = fmaxf(cnt[part * GG + g], 1.0f);
        ro[t] = pool[(part * GG + g) * 64 + (j & 63)] / c;
    }
    __syncthreads();
    for (int t = tid; t < GG * 64; t += 256) {
        int g = t >> 6;
        int i = t & 63;
        float s = b1[i];
        for (int j = 0; j < 128; j++) s = fmaf(ro[g * 128 + j], w1[i * 128 + j], s);
        hid[t] = fmaxf(s, 0.f);
    }
    __syncthreads();
    if (tid < GG) {
        float s = b2[0];
        for (int i = 0; i < 64; i++) s = fmaf(hid[tid * 64 + i], w2[i], s);
        out[tid] = s;
    }
}

extern "C" void kernel_launch(void* const* d_in, const int* in_sizes, int n_in,
                              void* d_out, int out_size, void* d_ws, size_t ws_size,
                              hipStream_t stream) {
    const float* x       = (const float*)d_in[0];
    const int*   ei      = (const int*)d_in[1];
    const int*   ntype   = (const int*)d_in[2];
    const float* eattr   = (const float*)d_in[3];
    const int*   batch   = (const int*)d_in[4];
    const float* sage_wl = (const float*)d_in[5];
    const float* sage_bl = (const float*)d_in[6];
    const float* sage_wr = (const float*)d_in[7];
    const float* mlp_w1  = (const float*)d_in[8];
    const float* mlp_b1  = (const float*)d_in[9];
    const float* mlp_w2  = (const float*)d_in[10];
    const float* mlp_b2  = (const float*)d_in[11];
    const float* gw[3]  = {(const float*)d_in[12], (const float*)d_in[18], (const float*)d_in[24]};
    const float* gas[3] = {(const float*)d_in[13], (const float*)d_in[19], (const float*)d_in[25]};
    const float* gad[3] = {(const float*)d_in[14], (const float*)d_in[20], (const float*)d_in[26]};
    const float* gwe[3] = {(const float*)d_in[15], (const float*)d_in[21], (const float*)d_in[27]};
    const float* gae[3] = {(const float*)d_in[16], (const float*)d_in[22], (const float*)d_in[28]};
    const float* gb[3]  = {(const float*)d_in[17], (const float*)d_in[23], (const float*)d_in[29]};

    char* base = (char*)d_ws;
    size_t o = 0;
    auto alloc = [&](size_t bytes) -> char* {
        char* p = base + o;
        o = (o + bytes + 255) & ~(size_t)255;
        return p;
    };
    int*   deg     = (int*)  alloc(NN * 4);
    float* esum    = (float*)alloc(NN * 4);
    float* mean_e  = (float*)alloc(NN * 4);
    float* inv_deg = (float*)alloc(NN * 4);
    int*   row_off = (int*)  alloc((NN + 1) * 4);
    int*   pos     = (int*)  alloc(NN * 4);
    int*   bsum    = (int*)  alloc(64 * 4);
    int*   boff    = (int*)  alloc(64 * 4);
    int*   csr_src = (int*)  alloc((size_t)EE * 4);
    float* csr_e   = (float*)alloc((size_t)EE * 4);
    float* xl      = (float*)alloc((size_t)NN * 64 * 4);
    float* xr      = (float*)alloc((size_t)NN * 64 * 4);
    float* hA      = (float*)alloc((size_t)NN * 64 * 4);
    float* hB      = (float*)alloc((size_t)NN * 64 * 4);
    float* hproj   = (float*)alloc((size_t)NN * 128 * 4);
    float* sval    = (float*)alloc((size_t)NN * 2 * 4);
    float* dval    = (float*)alloc((size_t)NN * 2 * 4);
    float* wt      = (float*)alloc(256 * 128 * 4);
    float* wtg     = (float*)alloc(64 * 128 * 4);
    float* asw     = (float*)alloc(128 * 4);
    float* adw     = (float*)alloc(128 * 4);
    float* wedot   = (float*)alloc(2 * 4);
    float* pools   = (float*)alloc(2 * GG * 64 * 4);
    float* cnt     = (float*)alloc(2 * GG * 4);

    hipMemsetAsync(deg, 0, NN * 4, stream);
    hipMemsetAsync(esum, 0, NN * 4, stream);
    hipMemsetAsync(pools, 0, 2 * GG * 64 * 4, stream);
    hipMemsetAsync(cnt, 0, 2 * GG * 4, stream);

    deg_kernel<<<EE / 256, 256, 0, stream>>>(ei, eattr, deg, esum);
    scan1_kernel<<<SCAN_NB, 1024, 0, stream>>>(deg, row_off, bsum);
    scan2_kernel<<<1, 64, 0, stream>>>(bsum, boff, row_off);
    scan3_kernel<<<SCAN_NB, 1024, 0, stream>>>(deg, esum, boff, row_off, pos, mean_e, inv_deg);
    fill_kernel<<<EE / 256, 256, 0, stream>>>(ei, eattr, pos, csr_src, csr_e);

    transpose2_kernel<<<256, 128, 0, stream>>>(sage_wl, sage_wr, wt);
    sage_mm_kernel<<<NN / SMT, 256, 0, stream>>>(x, wt, xl, xr);
    sage_agg_kernel<<<NN / 4, 256, 0, stream>>>(xl, xr, sage_bl, inv_deg, row_off, csr_src, hA);

    float* hin = hA;
    float* hout = hB;
    for (int L = 0; L < 3; ++L) {
        int H = (L == 2) ? 1 : 2;
        int H64 = H * 64;
        transpose_gat_kernel<<<64, 128, 0, stream>>>(gw[L], gas[L], gad[L], gwe[L], gae[L],
                                                     wtg, asw, adw, wedot, H64);
        if (H == 2)
            proj_mm_kernel<2><<<NN / SMT, 256, 0, stream>>>(hin, wtg, hproj);
        else
            proj_mm_kernel<1><<<NN / SMT, 256, 0, stream>>>(hin, wtg, hproj);
        attval_kernel<<<NN / 4, 256, 0, stream>>>(hin, asw, adw, sval, dval, H);
        gat_kernel<<<NN / 4, 256, 0, stream>>>(hproj, sval, dval, wedot, gb[L],
                                               mean_e, row_off, csr_src, csr_e, hout, H);
        float* tmp = hin; hin = hout; hout = tmp;
    }
    // final features now in hin
    pool_kernel<<<512, 256, 0, stream>>>(hin, ntype, batch, pools, cnt);
    mlp_kernel<<<1, 256, 0, stream>>>(pools, cnt, mlp_w1, mlp_b1, mlp_w2, mlp_b2, (float*)d_out);
}

// Round 8
// 615.020 us; speedup vs baseline: 2.0630x; 1.0114x over previous
//
#include <hip/hip_runtime.h>
#include <hip/hip_bf16.h>

#define NN 50000
#define EE 800000
#define GG 16
#define IN_DIM 256
#define HID 64
#define NEG 0.2f
#define SCAN_NB 49   // ceil(50000/1024)
#define SMT 40       // nodes per matmul block (50000 = 1250*40)

__device__ inline float wred_sum(float v) {
    for (int o = 32; o > 0; o >>= 1) v += __shfl_xor(v, o, 64);
    return v;
}
__device__ inline float wred_max(float v) {
    for (int o = 32; o > 0; o >>= 1) v = fmaxf(v, __shfl_xor(v, o, 64));
    return v;
}
// sum float4 across the 4 slot groups (lanes differing in bits 4,5)
__device__ inline void slot_reduce4(float4& a) {
    a.x += __shfl_xor(a.x, 16, 64); a.y += __shfl_xor(a.y, 16, 64);
    a.z += __shfl_xor(a.z, 16, 64); a.w += __shfl_xor(a.w, 16, 64);
    a.x += __shfl_xor(a.x, 32, 64); a.y += __shfl_xor(a.y, 32, 64);
    a.z += __shfl_xor(a.z, 32, 64); a.w += __shfl_xor(a.w, 32, 64);
}

__device__ inline float lrelu(float a) { return a > 0.f ? a : NEG * a; }

// ---- degree + edge_attr sum per dst ----
__global__ __launch_bounds__(256) void deg_kernel(const int* __restrict__ ei,
                                                  const float* __restrict__ eattr,
                                                  int* __restrict__ deg,
                                                  float* __restrict__ esum) {
    int e = blockIdx.x * 256 + threadIdx.x;
    if (e >= EE) return;
    int d = ei[EE + e];
    atomicAdd(&deg[d], 1);
    atomicAdd(&esum[d], eattr[e]);
}

// ---- scan stage 1: per-block exclusive scan of deg, block totals ----
__global__ __launch_bounds__(1024) void scan1_kernel(const int* __restrict__ deg,
                                                     int* __restrict__ row_off,
                                                     int* __restrict__ bsum) {
    __shared__ int buf[1024];
    int b = blockIdx.x;
    int i = b * 1024 + threadIdx.x;
    int v = (i < NN) ? deg[i] : 0;
    buf[threadIdx.x] = v;
    __syncthreads();
    for (int ofs = 1; ofs < 1024; ofs <<= 1) {
        int t = (threadIdx.x >= ofs) ? buf[threadIdx.x - ofs] : 0;
        __syncthreads();
        buf[threadIdx.x] += t;
        __syncthreads();
    }
    if (i < NN) row_off[i] = buf[threadIdx.x] - v;   // local exclusive
    if (threadIdx.x == 1023) bsum[b] = buf[1023];
}

// ---- scan stage 2: single-wave scan of block totals ----
__global__ __launch_bounds__(64) void scan2_kernel(const int* __restrict__ bsum,
                                                   int* __restrict__ boff,
                                                   int* __restrict__ row_off) {
    int l = threadIdx.x;
    int v = (l < SCAN_NB) ? bsum[l] : 0;
    int incl = v;
    for (int ofs = 1; ofs < 64; ofs <<= 1) {
        int t = __shfl_up(incl, ofs, 64);
        if (l >= ofs) incl += t;
    }
    if (l < SCAN_NB) boff[l] = incl - v;
    if (l == 63) row_off[NN] = incl;
}

// ---- scan stage 3: apply block offsets, derive pos/inv_deg/mean_e ----
__global__ __launch_bounds__(1024) void scan3_kernel(const int* __restrict__ deg,
                                                     const float* __restrict__ esum,
                                                     const int* __restrict__ boff,
                                                     int* __restrict__ row_off,
                                                     int* __restrict__ pos,
                                                     float* __restrict__ mean_e,
                                                     float* __restrict__ inv_deg) {
    int b = blockIdx.x;
    int i = b * 1024 + threadIdx.x;
    if (i >= NN) return;
    int ro = row_off[i] + boff[b];
    row_off[i] = ro;
    pos[i] = ro;
    float idg = 1.0f / fmaxf((float)deg[i], 1.0f);
    inv_deg[i] = idg;
    mean_e[i] = esum[i] * idg;
}

// ---- fill CSR buckets ----
__global__ __launch_bounds__(256) void fill_kernel(const int* __restrict__ ei,
                                                   const float* __restrict__ eattr,
                                                   int* __restrict__ pos,
                                                   int* __restrict__ csr_src,
                                                   float* __restrict__ csr_e) {
    int e = blockIdx.x * 256 + threadIdx.x;
    if (e >= EE) return;
    int d = ei[EE + e];
    int p = atomicAdd(&pos[d], 1);
    csr_src[p] = ei[e];
    csr_e[p] = eattr[e];
}

// ---- transpose+pack sage weights: wtp[(k>>2)*512 + j*4 + (k&3)] = [wl|wr][j][k] ----
__global__ void transpose2_kernel(const float* __restrict__ wl,
                                  const float* __restrict__ wr,
                                  float* __restrict__ wtp) {
    int k = blockIdx.x;      // 0..255
    int j = threadIdx.x;     // 0..127
    float v = (j < 64) ? wl[j * 256 + k] : wr[(j - 64) * 256 + k];
    wtp[(k >> 2) * 512 + j * 4 + (k & 3)] = v;
}

// ---- transpose+pack gat weight + fold attention vectors through W ----
__global__ void transpose_gat_kernel(const float* __restrict__ w,
                                     const float* __restrict__ a_s,
                                     const float* __restrict__ a_d,
                                     const float* __restrict__ we,
                                     const float* __restrict__ ae,
                                     float* __restrict__ wtgp,
                                     float* __restrict__ asw,
                                     float* __restrict__ adw,
                                     float* __restrict__ wedot, int H64) {
    int k = blockIdx.x;   // 0..63
    int j = threadIdx.x;  // 0..127  (= h*64 + c)
    if (j >= H64) return;
    int h = j >> 6;
    int c = j & 63;
    float wv = w[j * 64 + k];
    wtgp[(k >> 2) * (H64 * 4) + j * 4 + (k & 3)] = wv;
    float sv = wred_sum(wv * a_s[j]);
    float dv = wred_sum(wv * a_d[j]);
    if (c == 0) {
        asw[h * 64 + k] = sv;
        adw[h * 64 + k] = dv;
    }
    if (k == 0) {
        float wd = wred_sum(we[j] * ae[j]);
        if (c == 0) wedot[h] = wd;
    }
}

// ---- x @ [wl|wr].T : N x 256 -> N x 128 (xl, xr); 2 cols/thread, 40 nodes/block ----
__global__ __launch_bounds__(256) void sage_mm_kernel(const float* __restrict__ x,
                                                      const float* __restrict__ wtp,
                                                      float* __restrict__ xl,
                                                      float* __restrict__ xr) {
    __shared__ float xs[SMT * 256];
    int node0 = blockIdx.x * SMT;
    const float4* x4 = (const float4*)(x + (size_t)node0 * 256);
    float4* xs4 = (float4*)xs;
    for (int t = threadIdx.x; t < SMT * 64; t += 256) xs4[t] = x4[t];
    __syncthreads();
    int jj = threadIdx.x & 63;
    int g = threadIdx.x >> 6;           // node group: 10 nodes each
    float accL[10], accR[10];
#pragma unroll
    for (int n = 0; n < 10; n++) { accL[n] = 0.f; accR[n] = 0.f; }
    for (int k4 = 0; k4 < 64; k4++) {
        const float4 wL = *(const float4*)&wtp[k4 * 512 + jj * 4];
        const float4 wR = *(const float4*)&wtp[k4 * 512 + (jj + 64) * 4];
#pragma unroll
        for (int n = 0; n < 10; n++) {
            const float4 xv = xs4[(g * 10 + n) * 64 + k4];
            accL[n] = fmaf(xv.x, wL.x, accL[n]);
            accL[n] = fmaf(xv.y, wL.y, accL[n]);
            accL[n] = fmaf(xv.z, wL.z, accL[n]);
            accL[n] = fmaf(xv.w, wL.w, accL[n]);
            accR[n] = fmaf(xv.x, wR.x, accR[n]);
            accR[n] = fmaf(xv.y, wR.y, accR[n]);
            accR[n] = fmaf(xv.z, wR.z, accR[n]);
            accR[n] = fmaf(xv.w, wR.w, accR[n]);
        }
    }
#pragma unroll
    for (int n = 0; n < 10; n++) {
        int node = node0 + g * 10 + n;
        xl[(size_t)node * 64 + jj] = accL[n];
        xr[(size_t)node * 64 + jj] = accR[n];
    }
}

// ---- h @ W.T for GAT: pure GEMM, no cross-lane epilogue ----
template <int H>
__global__ __launch_bounds__(256) void proj_mm_kernel(const float* __restrict__ hin,
                                                      const float* __restrict__ wtgp,
                                                      float* __restrict__ hproj) {
    __shared__ float xs[SMT * 64];
    int node0 = blockIdx.x * SMT;
    const float4* h4 = (const float4*)(hin + (size_t)node0 * 64);
    float4* xs4 = (float4*)xs;
    for (int t = threadIdx.x; t < SMT * 16; t += 256) xs4[t] = h4[t];
    __syncthreads();
    int jj = threadIdx.x & 63;
    int g = threadIdx.x >> 6;
    float acc[H][10];
#pragma unroll
    for (int h = 0; h < H; h++)
#pragma unroll
        for (int n = 0; n < 10; n++) acc[h][n] = 0.f;
#pragma unroll 4
    for (int k4 = 0; k4 < 16; k4++) {
        float4 wv[H];
#pragma unroll
        for (int h = 0; h < H; h++)
            wv[h] = *(const float4*)&wtgp[k4 * (H * 256) + (h * 64 + jj) * 4];
#pragma unroll
        for (int n = 0; n < 10; n++) {
            const float4 xv = xs4[(g * 10 + n) * 16 + k4];
#pragma unroll
            for (int h = 0; h < H; h++) {
                acc[h][n] = fmaf(xv.x, wv[h].x, acc[h][n]);
                acc[h][n] = fmaf(xv.y, wv[h].y, acc[h][n]);
                acc[h][n] = fmaf(xv.z, wv[h].z, acc[h][n]);
                acc[h][n] = fmaf(xv.w, wv[h].w, acc[h][n]);
            }
        }
    }
#pragma unroll
    for (int h = 0; h < H; h++)
#pragma unroll
        for (int n = 0; n < 10; n++)
            hproj[(size_t)(node0 + g * 10 + n) * (H * 64) + h * 64 + jj] = acc[h][n];
}

// ---- per-(node,head) attention scalars from hin @ asw / adw (wave per node) ----
__global__ __launch_bounds__(256) void attval_kernel(const float* __restrict__ hin,
                                                     const float* __restrict__ asw,
                                                     const float* __restrict__ adw,
                                                     float* __restrict__ sval,
                                                     float* __restrict__ dval, int H) {
    int wid = (blockIdx.x * 256 + threadIdx.x) >> 6;
    int lane = threadIdx.x & 63;
    if (wid >= NN) return;
    float hv = hin[(size_t)wid * 64 + lane];
    for (int h = 0; h < H; ++h) {
        float sv = wred_sum(hv * asw[h * 64 + lane]);
        float dv = wred_sum(hv * adw[h * 64 + lane]);
        if (lane == 0) {
            sval[wid * H + h] = sv;
            dval[wid * H + h] = dv;
        }
    }
}

// ---- SAGE aggregation + combine + relu (4 edges in flight via slot layout) ----
__global__ __launch_bounds__(256) void sage_agg_kernel(const float* __restrict__ xl,
                                                       const float* __restrict__ xr,
                                                       const float* __restrict__ bl,
                                                       const float* __restrict__ inv_deg,
                                                       const int* __restrict__ row_off,
                                                       const int* __restrict__ csr_src,
                                                       float* __restrict__ hout) {
    int wid = blockIdx.x * 4 + (threadIdx.x >> 6);
    int lane = threadIdx.x & 63;
    if (wid >= NN) return;
    int slot = lane >> 4;
    int c4 = lane & 15;
    int r0 = row_off[wid], r1 = row_off[wid + 1];
    float4 acc = make_float4(0.f, 0.f, 0.f, 0.f);
    // unroll duplicates the body; fma/add chain order per lane is unchanged
#pragma unroll 4
    for (int idx = r0 + slot; idx < r1; idx += 4) {
        int s = csr_src[idx];
        const float4 hp = *(const float4*)&xl[(size_t)s * 64 + c4 * 4];
        acc.x += hp.x; acc.y += hp.y; acc.z += hp.z; acc.w += hp.w;
    }
    slot_reduce4(acc);
    if (slot == 0) {
        float idg = inv_deg[wid];
        const float4 b4 = *(const float4*)&bl[c4 * 4];
        const float4 xr4 = *(const float4*)&xr[(size_t)wid * 64 + c4 * 4];
        float4 v;
        v.x = fmaxf(acc.x * idg + b4.x + xr4.x, 0.f);
        v.y = fmaxf(acc.y * idg + b4.y + xr4.y, 0.f);
        v.z = fmaxf(acc.z * idg + b4.z + xr4.z, 0.f);
        v.w = fmaxf(acc.w * idg + b4.w + xr4.w, 0.f);
        *(float4*)&hout[(size_t)wid * 64 + c4 * 4] = v;
    }
}

// ---- GAT: round-5 verbatim (online softmax + 4-edge-slot weighted aggregate),
//      with only #pragma unroll 4 on the gather loop (FP order preserved). ----
__global__ __launch_bounds__(256) void gat_kernel(const float* __restrict__ hproj,
                                                  const float* __restrict__ sval,
                                                  const float* __restrict__ dval,
                                                  const float* __restrict__ wedot_buf,
                                                  const float* __restrict__ bias,
                                                  const float* __restrict__ mean_e,
                                                  const int* __restrict__ row_off,
                                                  const int* __restrict__ csr_src,
                                                  const float* __restrict__ csr_e,
                                                  float* __restrict__ hout, int H) {
    int wid = blockIdx.x * 4 + (threadIdx.x >> 6);
    int lane = threadIdx.x & 63;
    if (wid >= NN) return;
    int slot = lane >> 4;
    int c4 = lane & 15;
    int H64 = H * 64;
    int r0 = row_off[wid], r1 = row_off[wid + 1];
    float me = mean_e[wid];
    float4 acc = make_float4(0.f, 0.f, 0.f, 0.f);
    for (int h = 0; h < H; ++h) {
        float wedot = wedot_buf[h];
        float dv = dval[wid * H + h];
        float a_self = lrelu(sval[wid * H + h] + dv + me * wedot);
        // single pass: online max + denom, lane-strided
        float m_l = -INFINITY, den_l = 0.f;
        for (int idx = r0 + lane; idx < r1; idx += 64) {
            int s = csr_src[idx];
            float a = lrelu(sval[s * H + h] + dv + csr_e[idx] * wedot);
            float mn = fmaxf(m_l, a);
            den_l = den_l * __expf(m_l - mn) + __expf(a - mn);
            m_l = mn;
        }
        float m = fmaxf(wred_max(m_l), a_self);
        float den = wred_sum(den_l * __expf(m_l - m)) + __expf(a_self - m);
        float inv_den = 1.0f / den;
        // weighted gather: 4 edges in flight (one per slot), float4 per lane
#pragma unroll 4
        for (int idx = r0 + slot; idx < r1; idx += 4) {
            int s = csr_src[idx];
            float a = lrelu(sval[s * H + h] + dv + csr_e[idx] * wedot);
            float c = __expf(a - m) * inv_den;
            const float4 hp = *(const float4*)&hproj[(size_t)s * H64 + h * 64 + c4 * 4];
            acc.x = fmaf(c, hp.x, acc.x);
            acc.y = fmaf(c, hp.y, acc.y);
            acc.z = fmaf(c, hp.z, acc.z);
            acc.w = fmaf(c, hp.w, acc.w);
        }
        if (slot == 0) {  // self-loop contribution
            float c = __expf(a_self - m) * inv_den;
            const float4 hp = *(const float4*)&hproj[(size_t)wid * H64 + h * 64 + c4 * 4];
            acc.x = fmaf(c, hp.x, acc.x);
            acc.y = fmaf(c, hp.y, acc.y);
            acc.z = fmaf(c, hp.z, acc.z);
            acc.w = fmaf(c, hp.w, acc.w);
        }
    }
    slot_reduce4(acc);
    if (slot == 0) {
        float invH = 1.0f / (float)H;
        const float4 b4 = *(const float4*)&bias[c4 * 4];
        float4 v;
        v.x = fmaxf(acc.x * invH + b4.x, 0.f);
        v.y = fmaxf(acc.y * invH + b4.y, 0.f);
        v.z = fmaxf(acc.z * invH + b4.z, 0.f);
        v.w = fmaxf(acc.w * invH + b4.w, 0.f);
        *(float4*)&hout[(size_t)wid * 64 + c4 * 4] = v;
    }
}

// ---- masked mean pool: batch sorted -> register accumulate, flush on boundary ----
__global__ __launch_bounds__(256) void pool_kernel(const float* __restrict__ h,
                                                   const int* __restrict__ ntype,
                                                   const int* __restrict__ batch,
                                                   float* __restrict__ pool,
                                                   float* __restrict__ cnt) {
    int nwaves = gridDim.x * 4;
    int wid = blockIdx.x * 4 + (threadIdx.x >> 6);
    int lane = threadIdx.x & 63;
    int chunk = (NN + nwaves - 1) / nwaves;
    int n0 = wid * chunk;
    int n1 = min(n0 + chunk, NN);
    if (n0 >= NN) return;
    float acc1 = 0.f, acc2 = 0.f;
    int c1 = 0, c2 = 0;
    int cur_g = batch[n0];
    for (int n = n0; n < n1; ++n) {
        int g = batch[n];
        if (g != cur_g) {
            if (c1) {
                atomicAdd(&pool[(0 * GG + cur_g) * 64 + lane], acc1);
                if (lane == 0) atomicAdd(&cnt[0 * GG + cur_g], (float)c1);
            }
            if (c2) {
                atomicAdd(&pool[(1 * GG + cur_g) * 64 + lane], acc2);
                if (lane == 0) atomicAdd(&cnt[1 * GG + cur_g], (float)c2);
            }
            acc1 = acc2 = 0.f;
            c1 = c2 = 0;
            cur_g = g;
        }
        int t = ntype[n];
        if (t == 1) { acc1 += h[n * 64 + lane]; c1++; }
        else if (t == 2) { acc2 += h[n * 64 + lane]; c2++; }
    }
    if (c1) {
        atomicAdd(&pool[(0 * GG + cur_g) * 64 + lane], acc1);
        if (lane == 0) atomicAdd(&cnt[0 * GG + cur_g], (float)c1);
    }
    if (c2) {
        atomicAdd(&pool[(1 * GG + cur_g) * 64 + lane], acc2);
        if (lane == 0) atomicAdd(&cnt[1 * GG + cur_g], (float)c2);
    }
}

// ---- final MLP ----
__global__ __launch_bounds__(256) void mlp_kernel(const float* __restrict__ pool,
                                                  const float* __restrict__ cnt,
                                                  const float* __restrict__ w1,
                                                  const float* __restrict__ b1,
                                                  const float* __restrict__ w2,
                                                  const float* __restrict__ b2,
                                                  float* __restrict__ out) {
    __shared__ float ro[GG * 128];
    __shared__ float hid[GG * 64];
    int tid = threadIdx.x;
    for (int t = tid; t < GG * 128; t += 256) {
        int g = t >> 7;
        int j = t & 127;
        int part = j >> 6;
        float c = fmaxf(cnt[part * GG + g], 1.0f);
        ro[t] = pool[(part * GG + g) * 64 + (j & 63)] / c;
    }
    __syncthreads();
    for (int t = tid; t < GG * 64; t += 256) {
        int g = t >> 6;
        int i = t & 63;
        float s = b1[i];
        for (int j = 0; j < 128; j++) s = fmaf(ro[g * 128 + j], w1[i * 128 + j], s);
        hid[t] = fmaxf(s, 0.f);
    }
    __syncthreads();
    if (tid < GG) {
        float s = b2[0];
        for (int i = 0; i < 64; i++) s = fmaf(hid[tid * 64 + i], w2[i], s);
        out[tid] = s;
    }
}

extern "C" void kernel_launch(void* const* d_in, const int* in_sizes, int n_in,
                              void* d_out, int out_size, void* d_ws, size_t ws_size,
                              hipStream_t stream) {
    const float* x       = (const float*)d_in[0];
    const int*   ei      = (const int*)d_in[1];
    const int*   ntype   = (const int*)d_in[2];
    const float* eattr   = (const float*)d_in[3];
    const int*   batch   = (const int*)d_in[4];
    const float* sage_wl = (const float*)d_in[5];
    const float* sage_bl = (const float*)d_in[6];
    const float* sage_wr = (const float*)d_in[7];
    const float* mlp_w1  = (const float*)d_in[8];
    const float* mlp_b1  = (const float*)d_in[9];
    const float* mlp_w2  = (const float*)d_in[10];
    const float* mlp_b2  = (const float*)d_in[11];
    const float* gw[3]  = {(const float*)d_in[12], (const float*)d_in[18], (const float*)d_in[24]};
    const float* gas[3] = {(const float*)d_in[13], (const float*)d_in[19], (const float*)d_in[25]};
    const float* gad[3] = {(const float*)d_in[14], (const float*)d_in[20], (const float*)d_in[26]};
    const float* gwe[3] = {(const float*)d_in[15], (const float*)d_in[21], (const float*)d_in[27]};
    const float* gae[3] = {(const float*)d_in[16], (const float*)d_in[22], (const float*)d_in[28]};
    const float* gb[3]  = {(const float*)d_in[17], (const float*)d_in[23], (const float*)d_in[29]};

    char* base = (char*)d_ws;
    size_t o = 0;
    auto alloc = [&](size_t bytes) -> char* {
        char* p = base + o;
        o = (o + bytes + 255) & ~(size_t)255;
        return p;
    };
    int*   deg     = (int*)  alloc(NN * 4);
    float* esum    = (float*)alloc(NN * 4);
    float* mean_e  = (float*)alloc(NN * 4);
    float* inv_deg = (float*)alloc(NN * 4);
    int*   row_off = (int*)  alloc((NN + 1) * 4);
    int*   pos     = (int*)  alloc(NN * 4);
    int*   bsum    = (int*)  alloc(64 * 4);
    int*   boff    = (int*)  alloc(64 * 4);
    int*   csr_src = (int*)  alloc((size_t)EE * 4);
    float* csr_e   = (float*)alloc((size_t)EE * 4);
    float* xl      = (float*)alloc((size_t)NN * 64 * 4);
    float* xr      = (float*)alloc((size_t)NN * 64 * 4);
    float* hA      = (float*)alloc((size_t)NN * 64 * 4);
    float* hB      = (float*)alloc((size_t)NN * 64 * 4);
    float* hproj   = (float*)alloc((size_t)NN * 128 * 4);
    float* sval    = (float*)alloc((size_t)NN * 2 * 4);
    float* dval    = (float*)alloc((size_t)NN * 2 * 4);
    float* wt      = (float*)alloc(256 * 128 * 4);
    float* wtg     = (float*)alloc(64 * 128 * 4);
    float* asw     = (float*)alloc(128 * 4);
    float* adw     = (float*)alloc(128 * 4);
    float* wedot   = (float*)alloc(2 * 4);
    float* pools   = (float*)alloc(2 * GG * 64 * 4);
    float* cnt     = (float*)alloc(2 * GG * 4);

    hipMemsetAsync(deg, 0, NN * 4, stream);
    hipMemsetAsync(esum, 0, NN * 4, stream);
    hipMemsetAsync(pools, 0, 2 * GG * 64 * 4, stream);
    hipMemsetAsync(cnt, 0, 2 * GG * 4, stream);

    deg_kernel<<<EE / 256, 256, 0, stream>>>(ei, eattr, deg, esum);
    scan1_kernel<<<SCAN_NB, 1024, 0, stream>>>(deg, row_off, bsum);
    scan2_kernel<<<1, 64, 0, stream>>>(bsum, boff, row_off);
    scan3_kernel<<<SCAN_NB, 1024, 0, stream>>>(deg, esum, boff, row_off, pos, mean_e, inv_deg);
    fill_kernel<<<EE / 256, 256, 0, stream>>>(ei, eattr, pos, csr_src, csr_e);

    transpose2_kernel<<<256, 128, 0, stream>>>(sage_wl, sage_wr, wt);
    sage_mm_kernel<<<NN / SMT, 256, 0, stream>>>(x, wt, xl, xr);
    sage_agg_kernel<<<NN / 4, 256, 0, stream>>>(xl, xr, sage_bl, inv_deg, row_off, csr_src, hA);

    float* hin = hA;
    float* hout = hB;
    for (int L = 0; L < 3; ++L) {
        int H = (L == 2) ? 1 : 2;
        int H64 = H * 64;
        transpose_gat_kernel<<<64, 128, 0, stream>>>(gw[L], gas[L], gad[L], gwe[L], gae[L],
                                                     wtg, asw, adw, wedot, H64);
        if (H == 2)
            proj_mm_kernel<2><<<NN / SMT, 256, 0, stream>>>(hin, wtg, hproj);
        else
            proj_mm_kernel<1><<<NN / SMT, 256, 0, stream>>>(hin, wtg, hproj);
        attval_kernel<<<NN / 4, 256, 0, stream>>>(hin, asw, adw, sval, dval, H);
        gat_kernel<<<NN / 4, 256, 0, stream>>>(hproj, sval, dval, wedot, gb[L],
                                               mean_e, row_off, csr_src, csr_e, hout, H);
        float* tmp = hin; hin = hout; hout = tmp;
    }
    // final features now in hin
    pool_kernel<<<512, 256, 0, stream>>>(hin, ntype, batch, pools, cnt);
    mlp_kernel<<<1, 256, 0, stream>>>(pools, cnt, mlp_w1, mlp_b1, mlp_w2, mlp_b2, (float*)d_out);
}

// Round 9
// 607.020 us; speedup vs baseline: 2.0902x; 1.0132x over previous
//
#include <hip/hip_runtime.h>
#include <hip/hip_bf16.h>

#define NN 50000
#define EE 800000
#define GG 16
#define IN_DIM 256
#define HID 64
#define NEG 0.2f
#define SCAN_NB 49   // ceil(50000/1024)
#define SMT 40       // nodes per matmul block (50000 = 1250*40)

__device__ inline float wred_sum(float v) {
    for (int o = 32; o > 0; o >>= 1) v += __shfl_xor(v, o, 64);
    return v;
}
__device__ inline float wred_max(float v) {
    for (int o = 32; o > 0; o >>= 1) v = fmaxf(v, __shfl_xor(v, o, 64));
    return v;
}
// sum float4 across the 4 slot groups (lanes differing in bits 4,5)
__device__ inline void slot_reduce4(float4& a) {
    a.x += __shfl_xor(a.x, 16, 64); a.y += __shfl_xor(a.y, 16, 64);
    a.z += __shfl_xor(a.z, 16, 64); a.w += __shfl_xor(a.w, 16, 64);
    a.x += __shfl_xor(a.x, 32, 64); a.y += __shfl_xor(a.y, 32, 64);
    a.z += __shfl_xor(a.z, 32, 64); a.w += __shfl_xor(a.w, 32, 64);
}

__device__ inline float lrelu(float a) { return a > 0.f ? a : NEG * a; }

// ---- degree + edge_attr sum per dst ----
__global__ __launch_bounds__(256) void deg_kernel(const int* __restrict__ ei,
                                                  const float* __restrict__ eattr,
                                                  int* __restrict__ deg,
                                                  float* __restrict__ esum) {
    int e = blockIdx.x * 256 + threadIdx.x;
    if (e >= EE) return;
    int d = ei[EE + e];
    atomicAdd(&deg[d], 1);
    atomicAdd(&esum[d], eattr[e]);
}

// ---- build list of nodes needed by the pool (ntype 1 or 2); order-free ----
__global__ __launch_bounds__(256) void build_sel_kernel(const int* __restrict__ ntype,
                                                        int* __restrict__ nodesel,
                                                        int* __restrict__ nsel) {
    int n = blockIdx.x * 256 + threadIdx.x;
    if (n >= NN) return;
    int t = ntype[n];
    if (t == 1 || t == 2) {
        int p = atomicAdd(nsel, 1);
        nodesel[p] = n;
    }
}

// ---- scan stage 1: per-block exclusive scan of deg, block totals ----
__global__ __launch_bounds__(1024) void scan1_kernel(const int* __restrict__ deg,
                                                     int* __restrict__ row_off,
                                                     int* __restrict__ bsum) {
    __shared__ int buf[1024];
    int b = blockIdx.x;
    int i = b * 1024 + threadIdx.x;
    int v = (i < NN) ? deg[i] : 0;
    buf[threadIdx.x] = v;
    __syncthreads();
    for (int ofs = 1; ofs < 1024; ofs <<= 1) {
        int t = (threadIdx.x >= ofs) ? buf[threadIdx.x - ofs] : 0;
        __syncthreads();
        buf[threadIdx.x] += t;
        __syncthreads();
    }
    if (i < NN) row_off[i] = buf[threadIdx.x] - v;   // local exclusive
    if (threadIdx.x == 1023) bsum[b] = buf[1023];
}

// ---- scan stage 2: single-wave scan of block totals ----
__global__ __launch_bounds__(64) void scan2_kernel(const int* __restrict__ bsum,
                                                   int* __restrict__ boff,
                                                   int* __restrict__ row_off) {
    int l = threadIdx.x;
    int v = (l < SCAN_NB) ? bsum[l] : 0;
    int incl = v;
    for (int ofs = 1; ofs < 64; ofs <<= 1) {
        int t = __shfl_up(incl, ofs, 64);
        if (l >= ofs) incl += t;
    }
    if (l < SCAN_NB) boff[l] = incl - v;
    if (l == 63) row_off[NN] = incl;
}

// ---- scan stage 3: apply block offsets, derive pos/inv_deg/mean_e ----
__global__ __launch_bounds__(1024) void scan3_kernel(const int* __restrict__ deg,
                                                     const float* __restrict__ esum,
                                                     const int* __restrict__ boff,
                                                     int* __restrict__ row_off,
                                                     int* __restrict__ pos,
                                                     float* __restrict__ mean_e,
                                                     float* __restrict__ inv_deg) {
    int b = blockIdx.x;
    int i = b * 1024 + threadIdx.x;
    if (i >= NN) return;
    int ro = row_off[i] + boff[b];
    row_off[i] = ro;
    pos[i] = ro;
    float idg = 1.0f / fmaxf((float)deg[i], 1.0f);
    inv_deg[i] = idg;
    mean_e[i] = esum[i] * idg;
}

// ---- fill CSR buckets ----
__global__ __launch_bounds__(256) void fill_kernel(const int* __restrict__ ei,
                                                   const float* __restrict__ eattr,
                                                   int* __restrict__ pos,
                                                   int* __restrict__ csr_src,
                                                   float* __restrict__ csr_e) {
    int e = blockIdx.x * 256 + threadIdx.x;
    if (e >= EE) return;
    int d = ei[EE + e];
    int p = atomicAdd(&pos[d], 1);
    csr_src[p] = ei[e];
    csr_e[p] = eattr[e];
}

// ---- ALL weight prep in one dispatch:
//      blocks 0..255   : sage transpose+pack  wtp[(k>>2)*512 + j*4 + (k&3)] = [wl|wr][j][k]
//      blocks 256..447 : gat layer (b-256)/64, k=(b-256)&63 : transpose+pack + folds ----
__global__ __launch_bounds__(128) void weights_kernel(const float* __restrict__ wl,
                                                      const float* __restrict__ wr,
                                                      float* __restrict__ wtp,
                                                      const float* __restrict__ w0,
                                                      const float* __restrict__ as0,
                                                      const float* __restrict__ ad0,
                                                      const float* __restrict__ we0,
                                                      const float* __restrict__ ae0,
                                                      const float* __restrict__ w1,
                                                      const float* __restrict__ as1,
                                                      const float* __restrict__ ad1,
                                                      const float* __restrict__ we1,
                                                      const float* __restrict__ ae1,
                                                      const float* __restrict__ w2,
                                                      const float* __restrict__ as2,
                                                      const float* __restrict__ ad2,
                                                      const float* __restrict__ we2,
                                                      const float* __restrict__ ae2,
                                                      float* __restrict__ wtg3,
                                                      float* __restrict__ asw3,
                                                      float* __restrict__ adw3,
                                                      float* __restrict__ wedot3) {
    int b = blockIdx.x;
    int j = threadIdx.x;     // 0..127
    if (b < 256) {
        int k = b;
        float v = (j < 64) ? wl[j * 256 + k] : wr[(j - 64) * 256 + k];
        wtp[(k >> 2) * 512 + j * 4 + (k & 3)] = v;
        return;
    }
    int L = (b - 256) >> 6;
    int k = (b - 256) & 63;
    const float* w  = (L == 0) ? w0  : (L == 1) ? w1  : w2;
    const float* as = (L == 0) ? as0 : (L == 1) ? as1 : as2;
    const float* ad = (L == 0) ? ad0 : (L == 1) ? ad1 : ad2;
    const float* we = (L == 0) ? we0 : (L == 1) ? we1 : we2;
    const float* ae = (L == 0) ? ae0 : (L == 1) ? ae1 : ae2;
    int H64 = (L == 2) ? 64 : 128;
    if (j >= H64) return;
    int h = j >> 6;
    int c = j & 63;
    float wv = w[j * 64 + k];
    wtg3[L * 8192 + (k >> 2) * (H64 * 4) + j * 4 + (k & 3)] = wv;
    float sv = wred_sum(wv * as[j]);
    float dv = wred_sum(wv * ad[j]);
    if (c == 0) {
        asw3[L * 128 + h * 64 + k] = sv;
        adw3[L * 128 + h * 64 + k] = dv;
    }
    if (k == 0) {
        float wd = wred_sum(we[j] * ae[j]);
        if (c == 0) wedot3[L * 2 + h] = wd;
    }
}

// ---- x @ [wl|wr].T : N x 256 -> N x 128 (xl, xr); 2 cols/thread, 40 nodes/block ----
__global__ __launch_bounds__(256) void sage_mm_kernel(const float* __restrict__ x,
                                                      const float* __restrict__ wtp,
                                                      float* __restrict__ xl,
                                                      float* __restrict__ xr) {
    __shared__ float xs[SMT * 256];
    int node0 = blockIdx.x * SMT;
    const float4* x4 = (const float4*)(x + (size_t)node0 * 256);
    float4* xs4 = (float4*)xs;
    for (int t = threadIdx.x; t < SMT * 64; t += 256) xs4[t] = x4[t];
    __syncthreads();
    int jj = threadIdx.x & 63;
    int g = threadIdx.x >> 6;           // node group: 10 nodes each
    float accL[10], accR[10];
#pragma unroll
    for (int n = 0; n < 10; n++) { accL[n] = 0.f; accR[n] = 0.f; }
    for (int k4 = 0; k4 < 64; k4++) {
        const float4 wL = *(const float4*)&wtp[k4 * 512 + jj * 4];
        const float4 wR = *(const float4*)&wtp[k4 * 512 + (jj + 64) * 4];
#pragma unroll
        for (int n = 0; n < 10; n++) {
            const float4 xv = xs4[(g * 10 + n) * 64 + k4];
            accL[n] = fmaf(xv.x, wL.x, accL[n]);
            accL[n] = fmaf(xv.y, wL.y, accL[n]);
            accL[n] = fmaf(xv.z, wL.z, accL[n]);
            accL[n] = fmaf(xv.w, wL.w, accL[n]);
            accR[n] = fmaf(xv.x, wR.x, accR[n]);
            accR[n] = fmaf(xv.y, wR.y, accR[n]);
            accR[n] = fmaf(xv.z, wR.z, accR[n]);
            accR[n] = fmaf(xv.w, wR.w, accR[n]);
        }
    }
#pragma unroll
    for (int n = 0; n < 10; n++) {
        int node = node0 + g * 10 + n;
        xl[(size_t)node * 64 + jj] = accL[n];
        xr[(size_t)node * 64 + jj] = accR[n];
    }
}

// ---- h @ W.T for GAT: pure GEMM, no cross-lane epilogue ----
template <int H>
__global__ __launch_bounds__(256) void proj_mm_kernel(const float* __restrict__ hin,
                                                      const float* __restrict__ wtgp,
                                                      float* __restrict__ hproj) {
    __shared__ float xs[SMT * 64];
    int node0 = blockIdx.x * SMT;
    const float4* h4 = (const float4*)(hin + (size_t)node0 * 64);
    float4* xs4 = (float4*)xs;
    for (int t = threadIdx.x; t < SMT * 16; t += 256) xs4[t] = h4[t];
    __syncthreads();
    int jj = threadIdx.x & 63;
    int g = threadIdx.x >> 6;
    float acc[H][10];
#pragma unroll
    for (int h = 0; h < H; h++)
#pragma unroll
        for (int n = 0; n < 10; n++) acc[h][n] = 0.f;
#pragma unroll 4
    for (int k4 = 0; k4 < 16; k4++) {
        float4 wv[H];
#pragma unroll
        for (int h = 0; h < H; h++)
            wv[h] = *(const float4*)&wtgp[k4 * (H * 256) + (h * 64 + jj) * 4];
#pragma unroll
        for (int n = 0; n < 10; n++) {
            const float4 xv = xs4[(g * 10 + n) * 16 + k4];
#pragma unroll
            for (int h = 0; h < H; h++) {
                acc[h][n] = fmaf(xv.x, wv[h].x, acc[h][n]);
                acc[h][n] = fmaf(xv.y, wv[h].y, acc[h][n]);
                acc[h][n] = fmaf(xv.z, wv[h].z, acc[h][n]);
                acc[h][n] = fmaf(xv.w, wv[h].w, acc[h][n]);
            }
        }
    }
#pragma unroll
    for (int h = 0; h < H; h++)
#pragma unroll
        for (int n = 0; n < 10; n++)
            hproj[(size_t)(node0 + g * 10 + n) * (H * 64) + h * 64 + jj] = acc[h][n];
}

// ---- per-(node,head) attention scalars from hin @ asw / adw (wave per node) ----
__global__ __launch_bounds__(256) void attval_kernel(const float* __restrict__ hin,
                                                     const float* __restrict__ asw,
                                                     const float* __restrict__ adw,
                                                     float* __restrict__ sval,
                                                     float* __restrict__ dval, int H) {
    int wid = (blockIdx.x * 256 + threadIdx.x) >> 6;
    int lane = threadIdx.x & 63;
    if (wid >= NN) return;
    float hv = hin[(size_t)wid * 64 + lane];
    for (int h = 0; h < H; ++h) {
        float sv = wred_sum(hv * asw[h * 64 + lane]);
        float dv = wred_sum(hv * adw[h * 64 + lane]);
        if (lane == 0) {
            sval[wid * H + h] = sv;
            dval[wid * H + h] = dv;
        }
    }
}

// ---- SAGE aggregation + combine + relu (4 edges in flight via slot layout) ----
__global__ __launch_bounds__(256) void sage_agg_kernel(const float* __restrict__ xl,
                                                       const float* __restrict__ xr,
                                                       const float* __restrict__ bl,
                                                       const float* __restrict__ inv_deg,
                                                       const int* __restrict__ row_off,
                                                       const int* __restrict__ csr_src,
                                                       float* __restrict__ hout) {
    int wid = blockIdx.x * 4 + (threadIdx.x >> 6);
    int lane = threadIdx.x & 63;
    if (wid >= NN) return;
    int slot = lane >> 4;
    int c4 = lane & 15;
    int r0 = row_off[wid], r1 = row_off[wid + 1];
    float4 acc = make_float4(0.f, 0.f, 0.f, 0.f);
    // unroll duplicates the body; fma/add chain order per lane is unchanged
#pragma unroll 4
    for (int idx = r0 + slot; idx < r1; idx += 4) {
        int s = csr_src[idx];
        const float4 hp = *(const float4*)&xl[(size_t)s * 64 + c4 * 4];
        acc.x += hp.x; acc.y += hp.y; acc.z += hp.z; acc.w += hp.w;
    }
    slot_reduce4(acc);
    if (slot == 0) {
        float idg = inv_deg[wid];
        const float4 b4 = *(const float4*)&bl[c4 * 4];
        const float4 xr4 = *(const float4*)&xr[(size_t)wid * 64 + c4 * 4];
        float4 v;
        v.x = fmaxf(acc.x * idg + b4.x + xr4.x, 0.f);
        v.y = fmaxf(acc.y * idg + b4.y + xr4.y, 0.f);
        v.z = fmaxf(acc.z * idg + b4.z + xr4.z, 0.f);
        v.w = fmaxf(acc.w * idg + b4.w + xr4.w, 0.f);
        *(float4*)&hout[(size_t)wid * 64 + c4 * 4] = v;
    }
}

// ---- GAT: round-5 body verbatim (passing codegen). Optional nodesel indirection
//      (layer 3 only) placed BEFORE any FP code; FP expressions untouched. ----
__global__ __launch_bounds__(256) void gat_kernel(const float* __restrict__ hproj,
                                                  const float* __restrict__ sval,
                                                  const float* __restrict__ dval,
                                                  const float* __restrict__ wedot_buf,
                                                  const float* __restrict__ bias,
                                                  const float* __restrict__ mean_e,
                                                  const int* __restrict__ row_off,
                                                  const int* __restrict__ csr_src,
                                                  const float* __restrict__ csr_e,
                                                  float* __restrict__ hout, int H,
                                                  const int* __restrict__ nodesel,
                                                  const int* __restrict__ nsel) {
    int wid = blockIdx.x * 4 + (threadIdx.x >> 6);
    int lane = threadIdx.x & 63;
    if (nodesel) {
        if (wid >= *nsel) return;
        wid = nodesel[wid];
    }
    if (wid >= NN) return;
    int slot = lane >> 4;
    int c4 = lane & 15;
    int H64 = H * 64;
    int r0 = row_off[wid], r1 = row_off[wid + 1];
    float me = mean_e[wid];
    float4 acc = make_float4(0.f, 0.f, 0.f, 0.f);
    for (int h = 0; h < H; ++h) {
        float wedot = wedot_buf[h];
        float dv = dval[wid * H + h];
        float a_self = lrelu(sval[wid * H + h] + dv + me * wedot);
        // single pass: online max + denom, lane-strided
        float m_l = -INFINITY, den_l = 0.f;
        for (int idx = r0 + lane; idx < r1; idx += 64) {
            int s = csr_src[idx];
            float a = lrelu(sval[s * H + h] + dv + csr_e[idx] * wedot);
            float mn = fmaxf(m_l, a);
            den_l = den_l * __expf(m_l - mn) + __expf(a - mn);
            m_l = mn;
        }
        float m = fmaxf(wred_max(m_l), a_self);
        float den = wred_sum(den_l * __expf(m_l - m)) + __expf(a_self - m);
        float inv_den = 1.0f / den;
        // weighted gather: 4 edges in flight (one per slot), float4 per lane
        for (int idx = r0 + slot; idx < r1; idx += 4) {
            int s = csr_src[idx];
            float a = lrelu(sval[s * H + h] + dv + csr_e[idx] * wedot);
            float c = __expf(a - m) * inv_den;
            const float4 hp = *(const float4*)&hproj[(size_t)s * H64 + h * 64 + c4 * 4];
            acc.x = fmaf(c, hp.x, acc.x);
            acc.y = fmaf(c, hp.y, acc.y);
            acc.z = fmaf(c, hp.z, acc.z);
            acc.w = fmaf(c, hp.w, acc.w);
        }
        if (slot == 0) {  // self-loop contribution
            float c = __expf(a_self - m) * inv_den;
            const float4 hp = *(const float4*)&hproj[(size_t)wid * H64 + h * 64 + c4 * 4];
            acc.x = fmaf(c, hp.x, acc.x);
            acc.y = fmaf(c, hp.y, acc.y);
            acc.z = fmaf(c, hp.z, acc.z);
            acc.w = fmaf(c, hp.w, acc.w);
        }
    }
    slot_reduce4(acc);
    if (slot == 0) {
        float invH = 1.0f / (float)H;
        const float4 b4 = *(const float4*)&bias[c4 * 4];
        float4 v;
        v.x = fmaxf(acc.x * invH + b4.x, 0.f);
        v.y = fmaxf(acc.y * invH + b4.y, 0.f);
        v.z = fmaxf(acc.z * invH + b4.z, 0.f);
        v.w = fmaxf(acc.w * invH + b4.w, 0.f);
        *(float4*)&hout[(size_t)wid * 64 + c4 * 4] = v;
    }
}

// ---- masked mean pool: batch sorted -> register accumulate, flush on boundary ----
__global__ __launch_bounds__(256) void pool_kernel(const float* __restrict__ h,
                                                   const int* __restrict__ ntype,
                                                   const int* __restrict__ batch,
                                                   float* __restrict__ pool,
                                                   float* __restrict__ cnt) {
    int nwaves = gridDim.x * 4;
    int wid = blockIdx.x * 4 + (threadIdx.x >> 6);
    int lane = threadIdx.x & 63;
    int chunk = (NN + nwaves - 1) / nwaves;
    int n0 = wid * chunk;
    int n1 = min(n0 + chunk, NN);
    if (n0 >= NN) return;
    float acc1 = 0.f, acc2 = 0.f;
    int c1 = 0, c2 = 0;
    int cur_g = batch[n0];
    for (int n = n0; n < n1; ++n) {
        int g = batch[n];
        if (g != cur_g) {
            if (c1) {
                atomicAdd(&pool[(0 * GG + cur_g) * 64 + lane], acc1);
                if (lane == 0) atomicAdd(&cnt[0 * GG + cur_g], (float)c1);
            }
            if (c2) {
                atomicAdd(&pool[(1 * GG + cur_g) * 64 + lane], acc2);
                if (lane == 0) atomicAdd(&cnt[1 * GG + cur_g], (float)c2);
            }
            acc1 = acc2 = 0.f;
            c1 = c2 = 0;
            cur_g = g;
        }
        int t = ntype[n];
        if (t == 1) { acc1 += h[n * 64 + lane]; c1++; }
        else if (t == 2) { acc2 += h[n * 64 + lane]; c2++; }
    }
    if (c1) {
        atomicAdd(&pool[(0 * GG + cur_g) * 64 + lane], acc1);
        if (lane == 0) atomicAdd(&cnt[0 * GG + cur_g], (float)c1);
    }
    if (c2) {
        atomicAdd(&pool[(1 * GG + cur_g) * 64 + lane], acc2);
        if (lane == 0) atomicAdd(&cnt[1 * GG + cur_g], (float)c2);
    }
}

// ---- final MLP ----
__global__ __launch_bounds__(256) void mlp_kernel(const float* __restrict__ pool,
                                                  const float* __restrict__ cnt,
                                                  const float* __restrict__ w1,
                                                  const float* __restrict__ b1,
                                                  const float* __restrict__ w2,
                                                  const float* __restrict__ b2,
                                                  float* __restrict__ out) {
    __shared__ float ro[GG * 128];
    __shared__ float hid[GG * 64];
    int tid = threadIdx.x;
    for (int t = tid; t < GG * 128; t += 256) {
        int g = t >> 7;
        int j = t & 127;
        int part = j >> 6;
        float c = fmaxf(cnt[part * GG + g], 1.0f);
        ro[t] = pool[(part * GG + g) * 64 + (j & 63)] / c;
    }
    __syncthreads();
    for (int t = tid; t < GG * 64; t += 256) {
        int g = t >> 6;
        int i = t & 63;
        float s = b1[i];
        for (int j = 0; j < 128; j++) s = fmaf(ro[g * 128 + j], w1[i * 128 + j], s);
        hid[t] = fmaxf(s, 0.f);
    }
    __syncthreads();
    if (tid < GG) {
        float s = b2[0];
        for (int i = 0; i < 64; i++) s = fmaf(hid[tid * 64 + i], w2[i], s);
        out[tid] = s;
    }
}

extern "C" void kernel_launch(void* const* d_in, const int* in_sizes, int n_in,
                              void* d_out, int out_size, void* d_ws, size_t ws_size,
                              hipStream_t stream) {
    const float* x       = (const float*)d_in[0];
    const int*   ei      = (const int*)d_in[1];
    const int*   ntype   = (const int*)d_in[2];
    const float* eattr   = (const float*)d_in[3];
    const int*   batch   = (const int*)d_in[4];
    const float* sage_wl = (const float*)d_in[5];
    const float* sage_bl = (const float*)d_in[6];
    const float* sage_wr = (const float*)d_in[7];
    const float* mlp_w1  = (const float*)d_in[8];
    const float* mlp_b1  = (const float*)d_in[9];
    const float* mlp_w2  = (const float*)d_in[10];
    const float* mlp_b2  = (const float*)d_in[11];
    const float* gw[3]  = {(const float*)d_in[12], (const float*)d_in[18], (const float*)d_in[24]};
    const float* gas[3] = {(const float*)d_in[13], (const float*)d_in[19], (const float*)d_in[25]};
    const float* gad[3] = {(const float*)d_in[14], (const float*)d_in[20], (const float*)d_in[26]};
    const float* gwe[3] = {(const float*)d_in[15], (const float*)d_in[21], (const float*)d_in[27]};
    const float* gae[3] = {(const float*)d_in[16], (const float*)d_in[22], (const float*)d_in[28]};
    const float* gb[3]  = {(const float*)d_in[17], (const float*)d_in[23], (const float*)d_in[29]};

    char* base = (char*)d_ws;
    size_t o = 0;
    auto alloc = [&](size_t bytes) -> char* {
        char* p = base + o;
        o = (o + bytes + 255) & ~(size_t)255;
        return p;
    };
    // deg + esum + nsel contiguous -> single memset
    char*  zblock1 = alloc((2 * (size_t)NN + 1) * 4);
    int*   deg     = (int*)zblock1;
    float* esum    = (float*)(zblock1 + (size_t)NN * 4);
    int*   nsel    = (int*)(zblock1 + 2 * (size_t)NN * 4);
    float* mean_e  = (float*)alloc(NN * 4);
    float* inv_deg = (float*)alloc(NN * 4);
    int*   row_off = (int*)  alloc((NN + 1) * 4);
    int*   pos     = (int*)  alloc(NN * 4);
    int*   bsum    = (int*)  alloc(64 * 4);
    int*   boff    = (int*)  alloc(64 * 4);
    int*   nodesel = (int*)  alloc(NN * 4);
    int*   csr_src = (int*)  alloc((size_t)EE * 4);
    float* csr_e   = (float*)alloc((size_t)EE * 4);
    float* xl      = (float*)alloc((size_t)NN * 64 * 4);
    float* xr      = (float*)alloc((size_t)NN * 64 * 4);
    float* hA      = (float*)alloc((size_t)NN * 64 * 4);
    float* hB      = (float*)alloc((size_t)NN * 64 * 4);
    float* hproj   = (float*)alloc((size_t)NN * 128 * 4);
    float* sval    = (float*)alloc((size_t)NN * 2 * 4);
    float* dval    = (float*)alloc((size_t)NN * 2 * 4);
    float* wt      = (float*)alloc(256 * 128 * 4);
    float* wtg3    = (float*)alloc(3 * 8192 * 4);
    float* asw3    = (float*)alloc(3 * 128 * 4);
    float* adw3    = (float*)alloc(3 * 128 * 4);
    float* wedot3  = (float*)alloc(3 * 2 * 4);
    // pools + cnt contiguous -> single memset
    char*  zblock2 = alloc((2 * GG * 64 + 2 * GG) * 4);
    float* pools   = (float*)zblock2;
    float* cnt     = (float*)(zblock2 + 2 * GG * 64 * 4);

    hipMemsetAsync(zblock1, 0, (2 * (size_t)NN + 1) * 4, stream);
    hipMemsetAsync(zblock2, 0, (2 * GG * 64 + 2 * GG) * 4, stream);

    weights_kernel<<<448, 128, 0, stream>>>(sage_wl, sage_wr, wt,
                                            gw[0], gas[0], gad[0], gwe[0], gae[0],
                                            gw[1], gas[1], gad[1], gwe[1], gae[1],
                                            gw[2], gas[2], gad[2], gwe[2], gae[2],
                                            wtg3, asw3, adw3, wedot3);
    deg_kernel<<<EE / 256, 256, 0, stream>>>(ei, eattr, deg, esum);
    build_sel_kernel<<<(NN + 255) / 256, 256, 0, stream>>>(ntype, nodesel, nsel);
    scan1_kernel<<<SCAN_NB, 1024, 0, stream>>>(deg, row_off, bsum);
    scan2_kernel<<<1, 64, 0, stream>>>(bsum, boff, row_off);
    scan3_kernel<<<SCAN_NB, 1024, 0, stream>>>(deg, esum, boff, row_off, pos, mean_e, inv_deg);
    fill_kernel<<<EE / 256, 256, 0, stream>>>(ei, eattr, pos, csr_src, csr_e);

    sage_mm_kernel<<<NN / SMT, 256, 0, stream>>>(x, wt, xl, xr);
    sage_agg_kernel<<<NN / 4, 256, 0, stream>>>(xl, xr, sage_bl, inv_deg, row_off, csr_src, hA);

    float* hin = hA;
    float* hout = hB;
    for (int L = 0; L < 3; ++L) {
        int H = (L == 2) ? 1 : 2;
        const float* wtgL = wtg3 + (size_t)L * 8192;
        const float* aswL = asw3 + L * 128;
        const float* adwL = adw3 + L * 128;
        const float* wedL = wedot3 + L * 2;
        if (H == 2)
            proj_mm_kernel<2><<<NN / SMT, 256, 0, stream>>>(hin, wtgL, hproj);
        else
            proj_mm_kernel<1><<<NN / SMT, 256, 0, stream>>>(hin, wtgL, hproj);
        attval_kernel<<<NN / 4, 256, 0, stream>>>(hin, aswL, adwL, sval, dval, H);
        gat_kernel<<<NN / 4, 256, 0, stream>>>(hproj, sval, dval, wedL, gb[L],
                                               mean_e, row_off, csr_src, csr_e, hout, H,
                                               (L == 2) ? nodesel : nullptr,
                                               (L == 2) ? nsel : nullptr);
        float* tmp = hin; hin = hout; hout = tmp;
    }
    // final features now in hin
    pool_kernel<<<512, 256, 0, stream>>>(hin, ntype, batch, pools, cnt);
    mlp_kernel<<<1, 256, 0, stream>>>(pools, cnt, mlp_w1, mlp_b1, mlp_w2, mlp_b2, (float*)d_out);
}

// Round 10
// 585.592 us; speedup vs baseline: 2.1667x; 1.0366x over previous
//
#include <hip/hip_runtime.h>
#include <hip/hip_bf16.h>

#define NN 50000
#define EE 800000
#define GG 16
#define IN_DIM 256
#define HID 64
#define NEG 0.2f
#define SCAN_NB 49   // ceil(50000/1024)
#define SMT 40       // nodes per matmul block (50000 = 1250*40)
#define PROJ_B (NN / SMT)   // 1250
#define ATT_B (NN / 4)      // 12500
#define EDGE_B (EE / 256)   // 3125
#define SEL_B ((NN + 255) / 256) // 196

__device__ inline float wred_sum(float v) {
    for (int o = 32; o > 0; o >>= 1) v += __shfl_xor(v, o, 64);
    return v;
}
__device__ inline float wred_max(float v) {
    for (int o = 32; o > 0; o >>= 1) v = fmaxf(v, __shfl_xor(v, o, 64));
    return v;
}
// sum float4 across the 4 slot groups (lanes differing in bits 4,5)
__device__ inline void slot_reduce4(float4& a) {
    a.x += __shfl_xor(a.x, 16, 64); a.y += __shfl_xor(a.y, 16, 64);
    a.z += __shfl_xor(a.z, 16, 64); a.w += __shfl_xor(a.w, 16, 64);
    a.x += __shfl_xor(a.x, 32, 64); a.y += __shfl_xor(a.y, 32, 64);
    a.z += __shfl_xor(a.z, 32, 64); a.w += __shfl_xor(a.w, 32, 64);
}

__device__ inline float lrelu(float a) { return a > 0.f ? a : NEG * a; }

// ---- FUSED: degree/esum accumulation (blocks 0..3124) + pool-node selection ----
__global__ __launch_bounds__(256) void deg_sel_kernel(const int* __restrict__ ei,
                                                      const float* __restrict__ eattr,
                                                      int* __restrict__ deg,
                                                      float* __restrict__ esum,
                                                      const int* __restrict__ ntype,
                                                      int* __restrict__ nodesel,
                                                      int* __restrict__ nsel) {
    int b = blockIdx.x;
    if (b < EDGE_B) {
        int e = b * 256 + threadIdx.x;
        if (e >= EE) return;
        int d = ei[EE + e];
        atomicAdd(&deg[d], 1);
        atomicAdd(&esum[d], eattr[e]);
        return;
    }
    int n = (b - EDGE_B) * 256 + threadIdx.x;
    if (n >= NN) return;
    int t = ntype[n];
    if (t == 1 || t == 2) {
        int p = atomicAdd(nsel, 1);
        nodesel[p] = n;
    }
}

// ---- scan stage 1: per-block exclusive scan of deg, block totals ----
__global__ __launch_bounds__(1024) void scan1_kernel(const int* __restrict__ deg,
                                                     int* __restrict__ row_off,
                                                     int* __restrict__ bsum) {
    __shared__ int buf[1024];
    int b = blockIdx.x;
    int i = b * 1024 + threadIdx.x;
    int v = (i < NN) ? deg[i] : 0;
    buf[threadIdx.x] = v;
    __syncthreads();
    for (int ofs = 1; ofs < 1024; ofs <<= 1) {
        int t = (threadIdx.x >= ofs) ? buf[threadIdx.x - ofs] : 0;
        __syncthreads();
        buf[threadIdx.x] += t;
        __syncthreads();
    }
    if (i < NN) row_off[i] = buf[threadIdx.x] - v;   // local exclusive
    if (threadIdx.x == 1023) bsum[b] = buf[1023];
}

// ---- scan stage 2: single-wave scan of block totals ----
__global__ __launch_bounds__(64) void scan2_kernel(const int* __restrict__ bsum,
                                                   int* __restrict__ boff,
                                                   int* __restrict__ row_off) {
    int l = threadIdx.x;
    int v = (l < SCAN_NB) ? bsum[l] : 0;
    int incl = v;
    for (int ofs = 1; ofs < 64; ofs <<= 1) {
        int t = __shfl_up(incl, ofs, 64);
        if (l >= ofs) incl += t;
    }
    if (l < SCAN_NB) boff[l] = incl - v;
    if (l == 63) row_off[NN] = incl;
}

// ---- scan stage 3: apply block offsets, derive pos/inv_deg/mean_e ----
__global__ __launch_bounds__(1024) void scan3_kernel(const int* __restrict__ deg,
                                                     const float* __restrict__ esum,
                                                     const int* __restrict__ boff,
                                                     int* __restrict__ row_off,
                                                     int* __restrict__ pos,
                                                     float* __restrict__ mean_e,
                                                     float* __restrict__ inv_deg) {
    int b = blockIdx.x;
    int i = b * 1024 + threadIdx.x;
    if (i >= NN) return;
    int ro = row_off[i] + boff[b];
    row_off[i] = ro;
    pos[i] = ro;
    float idg = 1.0f / fmaxf((float)deg[i], 1.0f);
    inv_deg[i] = idg;
    mean_e[i] = esum[i] * idg;
}

// ---- ALL weight prep in one dispatch (as round 9) ----
__global__ __launch_bounds__(128) void weights_kernel(const float* __restrict__ wl,
                                                      const float* __restrict__ wr,
                                                      float* __restrict__ wtp,
                                                      const float* __restrict__ w0,
                                                      const float* __restrict__ as0,
                                                      const float* __restrict__ ad0,
                                                      const float* __restrict__ we0,
                                                      const float* __restrict__ ae0,
                                                      const float* __restrict__ w1,
                                                      const float* __restrict__ as1,
                                                      const float* __restrict__ ad1,
                                                      const float* __restrict__ we1,
                                                      const float* __restrict__ ae1,
                                                      const float* __restrict__ w2,
                                                      const float* __restrict__ as2,
                                                      const float* __restrict__ ad2,
                                                      const float* __restrict__ we2,
                                                      const float* __restrict__ ae2,
                                                      float* __restrict__ wtg3,
                                                      float* __restrict__ asw3,
                                                      float* __restrict__ adw3,
                                                      float* __restrict__ wedot3) {
    int b = blockIdx.x;
    int j = threadIdx.x;     // 0..127
    if (b < 256) {
        int k = b;
        float v = (j < 64) ? wl[j * 256 + k] : wr[(j - 64) * 256 + k];
        wtp[(k >> 2) * 512 + j * 4 + (k & 3)] = v;
        return;
    }
    int L = (b - 256) >> 6;
    int k = (b - 256) & 63;
    const float* w  = (L == 0) ? w0  : (L == 1) ? w1  : w2;
    const float* as = (L == 0) ? as0 : (L == 1) ? as1 : as2;
    const float* ad = (L == 0) ? ad0 : (L == 1) ? ad1 : ad2;
    const float* we = (L == 0) ? we0 : (L == 1) ? we1 : we2;
    const float* ae = (L == 0) ? ae0 : (L == 1) ? ae1 : ae2;
    int H64 = (L == 2) ? 64 : 128;
    if (j >= H64) return;
    int h = j >> 6;
    int c = j & 63;
    float wv = w[j * 64 + k];
    wtg3[L * 8192 + (k >> 2) * (H64 * 4) + j * 4 + (k & 3)] = wv;
    float sv = wred_sum(wv * as[j]);
    float dv = wred_sum(wv * ad[j]);
    if (c == 0) {
        asw3[L * 128 + h * 64 + k] = sv;
        adw3[L * 128 + h * 64 + k] = dv;
    }
    if (k == 0) {
        float wd = wred_sum(we[j] * ae[j]);
        if (c == 0) wedot3[L * 2 + h] = wd;
    }
}

// ---- FUSED: sage_mm (blocks 0..1249, FMA-bound) + CSR fill (blocks 1250.., scatter-bound) ----
__global__ __launch_bounds__(256) void sage_fill_kernel(const float* __restrict__ x,
                                                        const float* __restrict__ wtp,
                                                        float* __restrict__ xl,
                                                        float* __restrict__ xr,
                                                        const int* __restrict__ ei,
                                                        const float* __restrict__ eattr,
                                                        int* __restrict__ pos,
                                                        int* __restrict__ csr_src,
                                                        float* __restrict__ csr_e) {
    __shared__ float xs[SMT * 256];
    if (blockIdx.x < PROJ_B) {
        int node0 = blockIdx.x * SMT;
        const float4* x4 = (const float4*)(x + (size_t)node0 * 256);
        float4* xs4 = (float4*)xs;
        for (int t = threadIdx.x; t < SMT * 64; t += 256) xs4[t] = x4[t];
        __syncthreads();
        int jj = threadIdx.x & 63;
        int g = threadIdx.x >> 6;           // node group: 10 nodes each
        float accL[10], accR[10];
#pragma unroll
        for (int n = 0; n < 10; n++) { accL[n] = 0.f; accR[n] = 0.f; }
        for (int k4 = 0; k4 < 64; k4++) {
            const float4 wL = *(const float4*)&wtp[k4 * 512 + jj * 4];
            const float4 wR = *(const float4*)&wtp[k4 * 512 + (jj + 64) * 4];
#pragma unroll
            for (int n = 0; n < 10; n++) {
                const float4 xv = xs4[(g * 10 + n) * 64 + k4];
                accL[n] = fmaf(xv.x, wL.x, accL[n]);
                accL[n] = fmaf(xv.y, wL.y, accL[n]);
                accL[n] = fmaf(xv.z, wL.z, accL[n]);
                accL[n] = fmaf(xv.w, wL.w, accL[n]);
                accR[n] = fmaf(xv.x, wR.x, accR[n]);
                accR[n] = fmaf(xv.y, wR.y, accR[n]);
                accR[n] = fmaf(xv.z, wR.z, accR[n]);
                accR[n] = fmaf(xv.w, wR.w, accR[n]);
            }
        }
#pragma unroll
        for (int n = 0; n < 10; n++) {
            int node = node0 + g * 10 + n;
            xl[(size_t)node * 64 + jj] = accL[n];
            xr[(size_t)node * 64 + jj] = accR[n];
        }
        return;
    }
    int e = (blockIdx.x - PROJ_B) * 256 + threadIdx.x;
    if (e >= EE) return;
    int d = ei[EE + e];
    int p = atomicAdd(&pos[d], 1);
    csr_src[p] = ei[e];
    csr_e[p] = eattr[e];
}

// ---- FUSED: proj_mm<H> (blocks 0..1249) + attval (blocks 1250..) ----
template <int H>
__global__ __launch_bounds__(256) void proj_attval_kernel(const float* __restrict__ hin,
                                                          const float* __restrict__ wtgp,
                                                          float* __restrict__ hproj,
                                                          const float* __restrict__ asw,
                                                          const float* __restrict__ adw,
                                                          float* __restrict__ sval,
                                                          float* __restrict__ dval) {
    __shared__ float xs[SMT * 64];
    if (blockIdx.x < PROJ_B) {
        int node0 = blockIdx.x * SMT;
        const float4* h4 = (const float4*)(hin + (size_t)node0 * 64);
        float4* xs4 = (float4*)xs;
        for (int t = threadIdx.x; t < SMT * 16; t += 256) xs4[t] = h4[t];
        __syncthreads();
        int jj = threadIdx.x & 63;
        int g = threadIdx.x >> 6;
        float acc[H][10];
#pragma unroll
        for (int h = 0; h < H; h++)
#pragma unroll
            for (int n = 0; n < 10; n++) acc[h][n] = 0.f;
#pragma unroll 4
        for (int k4 = 0; k4 < 16; k4++) {
            float4 wv[H];
#pragma unroll
            for (int h = 0; h < H; h++)
                wv[h] = *(const float4*)&wtgp[k4 * (H * 256) + (h * 64 + jj) * 4];
#pragma unroll
            for (int n = 0; n < 10; n++) {
                const float4 xv = xs4[(g * 10 + n) * 16 + k4];
#pragma unroll
                for (int h = 0; h < H; h++) {
                    acc[h][n] = fmaf(xv.x, wv[h].x, acc[h][n]);
                    acc[h][n] = fmaf(xv.y, wv[h].y, acc[h][n]);
                    acc[h][n] = fmaf(xv.z, wv[h].z, acc[h][n]);
                    acc[h][n] = fmaf(xv.w, wv[h].w, acc[h][n]);
                }
            }
        }
#pragma unroll
        for (int h = 0; h < H; h++)
#pragma unroll
            for (int n = 0; n < 10; n++)
                hproj[(size_t)(node0 + g * 10 + n) * (H * 64) + h * 64 + jj] = acc[h][n];
        return;
    }
    // attval body (verbatim)
    int wid = ((blockIdx.x - PROJ_B) * 256 + threadIdx.x) >> 6;
    int lane = threadIdx.x & 63;
    if (wid >= NN) return;
    float hv = hin[(size_t)wid * 64 + lane];
    for (int h = 0; h < H; ++h) {
        float sv = wred_sum(hv * asw[h * 64 + lane]);
        float dv = wred_sum(hv * adw[h * 64 + lane]);
        if (lane == 0) {
            sval[wid * H + h] = sv;
            dval[wid * H + h] = dv;
        }
    }
}

// ---- SAGE aggregation + combine + relu (4 edges in flight via slot layout) ----
__global__ __launch_bounds__(256) void sage_agg_kernel(const float* __restrict__ xl,
                                                       const float* __restrict__ xr,
                                                       const float* __restrict__ bl,
                                                       const float* __restrict__ inv_deg,
                                                       const int* __restrict__ row_off,
                                                       const int* __restrict__ csr_src,
                                                       float* __restrict__ hout) {
    int wid = blockIdx.x * 4 + (threadIdx.x >> 6);
    int lane = threadIdx.x & 63;
    if (wid >= NN) return;
    int slot = lane >> 4;
    int c4 = lane & 15;
    int r0 = row_off[wid], r1 = row_off[wid + 1];
    float4 acc = make_float4(0.f, 0.f, 0.f, 0.f);
    // unroll duplicates the body; fma/add chain order per lane is unchanged
#pragma unroll 4
    for (int idx = r0 + slot; idx < r1; idx += 4) {
        int s = csr_src[idx];
        const float4 hp = *(const float4*)&xl[(size_t)s * 64 + c4 * 4];
        acc.x += hp.x; acc.y += hp.y; acc.z += hp.z; acc.w += hp.w;
    }
    slot_reduce4(acc);
    if (slot == 0) {
        float idg = inv_deg[wid];
        const float4 b4 = *(const float4*)&bl[c4 * 4];
        const float4 xr4 = *(const float4*)&xr[(size_t)wid * 64 + c4 * 4];
        float4 v;
        v.x = fmaxf(acc.x * idg + b4.x + xr4.x, 0.f);
        v.y = fmaxf(acc.y * idg + b4.y + xr4.y, 0.f);
        v.z = fmaxf(acc.z * idg + b4.z + xr4.z, 0.f);
        v.w = fmaxf(acc.w * idg + b4.w + xr4.w, 0.f);
        *(float4*)&hout[(size_t)wid * 64 + c4 * 4] = v;
    }
}

// ---- GAT: round-5 body verbatim (passing codegen). Optional nodesel indirection
//      (layer 3 only) placed BEFORE any FP code; FP expressions untouched. ----
__global__ __launch_bounds__(256) void gat_kernel(const float* __restrict__ hproj,
                                                  const float* __restrict__ sval,
                                                  const float* __restrict__ dval,
                                                  const float* __restrict__ wedot_buf,
                                                  const float* __restrict__ bias,
                                                  const float* __restrict__ mean_e,
                                                  const int* __restrict__ row_off,
                                                  const int* __restrict__ csr_src,
                                                  const float* __restrict__ csr_e,
                                                  float* __restrict__ hout, int H,
                                                  const int* __restrict__ nodesel,
                                                  const int* __restrict__ nsel) {
    int wid = blockIdx.x * 4 + (threadIdx.x >> 6);
    int lane = threadIdx.x & 63;
    if (nodesel) {
        if (wid >= *nsel) return;
        wid = nodesel[wid];
    }
    if (wid >= NN) return;
    int slot = lane >> 4;
    int c4 = lane & 15;
    int H64 = H * 64;
    int r0 = row_off[wid], r1 = row_off[wid + 1];
    float me = mean_e[wid];
    float4 acc = make_float4(0.f, 0.f, 0.f, 0.f);
    for (int h = 0; h < H; ++h) {
        float wedot = wedot_buf[h];
        float dv = dval[wid * H + h];
        float a_self = lrelu(sval[wid * H + h] + dv + me * wedot);
        // single pass: online max + denom, lane-strided
        float m_l = -INFINITY, den_l = 0.f;
        for (int idx = r0 + lane; idx < r1; idx += 64) {
            int s = csr_src[idx];
            float a = lrelu(sval[s * H + h] + dv + csr_e[idx] * wedot);
            float mn = fmaxf(m_l, a);
            den_l = den_l * __expf(m_l - mn) + __expf(a - mn);
            m_l = mn;
        }
        float m = fmaxf(wred_max(m_l), a_self);
        float den = wred_sum(den_l * __expf(m_l - m)) + __expf(a_self - m);
        float inv_den = 1.0f / den;
        // weighted gather: 4 edges in flight (one per slot), float4 per lane
        for (int idx = r0 + slot; idx < r1; idx += 4) {
            int s = csr_src[idx];
            float a = lrelu(sval[s * H + h] + dv + csr_e[idx] * wedot);
            float c = __expf(a - m) * inv_den;
            const float4 hp = *(const float4*)&hproj[(size_t)s * H64 + h * 64 + c4 * 4];
            acc.x = fmaf(c, hp.x, acc.x);
            acc.y = fmaf(c, hp.y, acc.y);
            acc.z = fmaf(c, hp.z, acc.z);
            acc.w = fmaf(c, hp.w, acc.w);
        }
        if (slot == 0) {  // self-loop contribution
            float c = __expf(a_self - m) * inv_den;
            const float4 hp = *(const float4*)&hproj[(size_t)wid * H64 + h * 64 + c4 * 4];
            acc.x = fmaf(c, hp.x, acc.x);
            acc.y = fmaf(c, hp.y, acc.y);
            acc.z = fmaf(c, hp.z, acc.z);
            acc.w = fmaf(c, hp.w, acc.w);
        }
    }
    slot_reduce4(acc);
    if (slot == 0) {
        float invH = 1.0f / (float)H;
        const float4 b4 = *(const float4*)&bias[c4 * 4];
        float4 v;
        v.x = fmaxf(acc.x * invH + b4.x, 0.f);
        v.y = fmaxf(acc.y * invH + b4.y, 0.f);
        v.z = fmaxf(acc.z * invH + b4.z, 0.f);
        v.w = fmaxf(acc.w * invH + b4.w, 0.f);
        *(float4*)&hout[(size_t)wid * 64 + c4 * 4] = v;
    }
}

// ---- masked mean pool: batch sorted -> register accumulate, flush on boundary ----
__global__ __launch_bounds__(256) void pool_kernel(const float* __restrict__ h,
                                                   const int* __restrict__ ntype,
                                                   const int* __restrict__ batch,
                                                   float* __restrict__ pool,
                                                   float* __restrict__ cnt) {
    int nwaves = gridDim.x * 4;
    int wid = blockIdx.x * 4 + (threadIdx.x >> 6);
    int lane = threadIdx.x & 63;
    int chunk = (NN + nwaves - 1) / nwaves;
    int n0 = wid * chunk;
    int n1 = min(n0 + chunk, NN);
    if (n0 >= NN) return;
    float acc1 = 0.f, acc2 = 0.f;
    int c1 = 0, c2 = 0;
    int cur_g = batch[n0];
    for (int n = n0; n < n1; ++n) {
        int g = batch[n];
        if (g != cur_g) {
            if (c1) {
                atomicAdd(&pool[(0 * GG + cur_g) * 64 + lane], acc1);
                if (lane == 0) atomicAdd(&cnt[0 * GG + cur_g], (float)c1);
            }
            if (c2) {
                atomicAdd(&pool[(1 * GG + cur_g) * 64 + lane], acc2);
                if (lane == 0) atomicAdd(&cnt[1 * GG + cur_g], (float)c2);
            }
            acc1 = acc2 = 0.f;
            c1 = c2 = 0;
            cur_g = g;
        }
        int t = ntype[n];
        if (t == 1) { acc1 += h[n * 64 + lane]; c1++; }
        else if (t == 2) { acc2 += h[n * 64 + lane]; c2++; }
    }
    if (c1) {
        atomicAdd(&pool[(0 * GG + cur_g) * 64 + lane], acc1);
        if (lane == 0) atomicAdd(&cnt[0 * GG + cur_g], (float)c1);
    }
    if (c2) {
        atomicAdd(&pool[(1 * GG + cur_g) * 64 + lane], acc2);
        if (lane == 0) atomicAdd(&cnt[1 * GG + cur_g], (float)c2);
    }
}

// ---- final MLP ----
__global__ __launch_bounds__(256) void mlp_kernel(const float* __restrict__ pool,
                                                  const float* __restrict__ cnt,
                                                  const float* __restrict__ w1,
                                                  const float* __restrict__ b1,
                                                  const float* __restrict__ w2,
                                                  const float* __restrict__ b2,
                                                  float* __restrict__ out) {
    __shared__ float ro[GG * 128];
    __shared__ float hid[GG * 64];
    int tid = threadIdx.x;
    for (int t = tid; t < GG * 128; t += 256) {
        int g = t >> 7;
        int j = t & 127;
        int part = j >> 6;
        float c = fmaxf(cnt[part * GG + g], 1.0f);
        ro[t] = pool[(part * GG + g) * 64 + (j & 63)] / c;
    }
    __syncthreads();
    for (int t = tid; t < GG * 64; t += 256) {
        int g = t >> 6;
        int i = t & 63;
        float s = b1[i];
        for (int j = 0; j < 128; j++) s = fmaf(ro[g * 128 + j], w1[i * 128 + j], s);
        hid[t] = fmaxf(s, 0.f);
    }
    __syncthreads();
    if (tid < GG) {
        float s = b2[0];
        for (int i = 0; i < 64; i++) s = fmaf(hid[tid * 64 + i], w2[i], s);
        out[tid] = s;
    }
}

extern "C" void kernel_launch(void* const* d_in, const int* in_sizes, int n_in,
                              void* d_out, int out_size, void* d_ws, size_t ws_size,
                              hipStream_t stream) {
    const float* x       = (const float*)d_in[0];
    const int*   ei      = (const int*)d_in[1];
    const int*   ntype   = (const int*)d_in[2];
    const float* eattr   = (const float*)d_in[3];
    const int*   batch   = (const int*)d_in[4];
    const float* sage_wl = (const float*)d_in[5];
    const float* sage_bl = (const float*)d_in[6];
    const float* sage_wr = (const float*)d_in[7];
    const float* mlp_w1  = (const float*)d_in[8];
    const float* mlp_b1  = (const float*)d_in[9];
    const float* mlp_w2  = (const float*)d_in[10];
    const float* mlp_b2  = (const float*)d_in[11];
    const float* gw[3]  = {(const float*)d_in[12], (const float*)d_in[18], (const float*)d_in[24]};
    const float* gas[3] = {(const float*)d_in[13], (const float*)d_in[19], (const float*)d_in[25]};
    const float* gad[3] = {(const float*)d_in[14], (const float*)d_in[20], (const float*)d_in[26]};
    const float* gwe[3] = {(const float*)d_in[15], (const float*)d_in[21], (const float*)d_in[27]};
    const float* gae[3] = {(const float*)d_in[16], (const float*)d_in[22], (const float*)d_in[28]};
    const float* gb[3]  = {(const float*)d_in[17], (const float*)d_in[23], (const float*)d_in[29]};

    char* base = (char*)d_ws;
    size_t o = 0;
    auto alloc = [&](size_t bytes) -> char* {
        char* p = base + o;
        o = (o + bytes + 255) & ~(size_t)255;
        return p;
    };
    // deg + esum + nsel contiguous -> single memset
    char*  zblock1 = alloc((2 * (size_t)NN + 1) * 4);
    int*   deg     = (int*)zblock1;
    float* esum    = (float*)(zblock1 + (size_t)NN * 4);
    int*   nsel    = (int*)(zblock1 + 2 * (size_t)NN * 4);
    float* mean_e  = (float*)alloc(NN * 4);
    float* inv_deg = (float*)alloc(NN * 4);
    int*   row_off = (int*)  alloc((NN + 1) * 4);
    int*   pos     = (int*)  alloc(NN * 4);
    int*   bsum    = (int*)  alloc(64 * 4);
    int*   boff    = (int*)  alloc(64 * 4);
    int*   nodesel = (int*)  alloc(NN * 4);
    int*   csr_src = (int*)  alloc((size_t)EE * 4);
    float* csr_e   = (float*)alloc((size_t)EE * 4);
    float* xl      = (float*)alloc((size_t)NN * 64 * 4);
    float* xr      = (float*)alloc((size_t)NN * 64 * 4);
    float* hA      = (float*)alloc((size_t)NN * 64 * 4);
    float* hB      = (float*)alloc((size_t)NN * 64 * 4);
    float* hproj   = (float*)alloc((size_t)NN * 128 * 4);
    float* sval    = (float*)alloc((size_t)NN * 2 * 4);
    float* dval    = (float*)alloc((size_t)NN * 2 * 4);
    float* wt      = (float*)alloc(256 * 128 * 4);
    float* wtg3    = (float*)alloc(3 * 8192 * 4);
    float* asw3    = (float*)alloc(3 * 128 * 4);
    float* adw3    = (float*)alloc(3 * 128 * 4);
    float* wedot3  = (float*)alloc(3 * 2 * 4);
    // pools + cnt contiguous -> single memset
    char*  zblock2 = alloc((2 * GG * 64 + 2 * GG) * 4);
    float* pools   = (float*)zblock2;
    float* cnt     = (float*)(zblock2 + 2 * GG * 64 * 4);

    hipMemsetAsync(zblock1, 0, (2 * (size_t)NN + 1) * 4, stream);
    hipMemsetAsync(zblock2, 0, (2 * GG * 64 + 2 * GG) * 4, stream);

    weights_kernel<<<448, 128, 0, stream>>>(sage_wl, sage_wr, wt,
                                            gw[0], gas[0], gad[0], gwe[0], gae[0],
                                            gw[1], gas[1], gad[1], gwe[1], gae[1],
                                            gw[2], gas[2], gad[2], gwe[2], gae[2],
                                            wtg3, asw3, adw3, wedot3);
    deg_sel_kernel<<<EDGE_B + SEL_B, 256, 0, stream>>>(ei, eattr, deg, esum,
                                                       ntype, nodesel, nsel);
    scan1_kernel<<<SCAN_NB, 1024, 0, stream>>>(deg, row_off, bsum);
    scan2_kernel<<<1, 64, 0, stream>>>(bsum, boff, row_off);
    scan3_kernel<<<SCAN_NB, 1024, 0, stream>>>(deg, esum, boff, row_off, pos, mean_e, inv_deg);

    // fused: sage projection (compute-bound) || CSR fill (scatter-bound)
    sage_fill_kernel<<<PROJ_B + EDGE_B, 256, 0, stream>>>(x, wt, xl, xr,
                                                          ei, eattr, pos, csr_src, csr_e);
    sage_agg_kernel<<<NN / 4, 256, 0, stream>>>(xl, xr, sage_bl, inv_deg, row_off, csr_src, hA);

    float* hin = hA;
    float* hout = hB;
    for (int L = 0; L < 3; ++L) {
        int H = (L == 2) ? 1 : 2;
        const float* wtgL = wtg3 + (size_t)L * 8192;
        const float* aswL = asw3 + L * 128;
        const float* adwL = adw3 + L * 128;
        const float* wedL = wedot3 + L * 2;
        if (H == 2)
            proj_attval_kernel<2><<<PROJ_B + ATT_B, 256, 0, stream>>>(hin, wtgL, hproj,
                                                                     aswL, adwL, sval, dval);
        else
            proj_attval_kernel<1><<<PROJ_B + ATT_B, 256, 0, stream>>>(hin, wtgL, hproj,
                                                                     aswL, adwL, sval, dval);
        gat_kernel<<<NN / 4, 256, 0, stream>>>(hproj, sval, dval, wedL, gb[L],
                                               mean_e, row_off, csr_src, csr_e, hout, H,
                                               (L == 2) ? nodesel : nullptr,
                                               (L == 2) ? nsel : nullptr);
        float* tmp = hin; hin = hout; hout = tmp;
    }
    // final features now in hin
    pool_kernel<<<512, 256, 0, stream>>>(hin, ntype, batch, pools, cnt);
    mlp_kernel<<<1, 256, 0, stream>>>(pools, cnt, mlp_w1, mlp_b1, mlp_w2, mlp_b2, (float*)d_out);
}